// Round 8
// baseline (346.702 us; speedup 1.0000x reference)
//
#include <hip/hip_runtime.h>

#define D 256
#define NC 64

using u16 = unsigned short;
using u32 = unsigned int;

typedef __attribute__((ext_vector_type(8))) short bfv8;   // 8 bf16 = 16 B
typedef __attribute__((ext_vector_type(4))) float f32x4;

__device__ __forceinline__ float bf2f(u32 u) {
  union { u32 i; float f; } v; v.i = u << 16; return v.f;
}
__device__ __forceinline__ u16 f2bf(float f) {
  union { float f; u32 i; } v; v.f = f;
  u32 x = v.i;
  return (u16)((x + 0x7FFFu + ((x >> 16) & 1u)) >> 16);  // RTNE
}
__device__ __forceinline__ u32 pk2(float a, float b) {
  return (u32)f2bf(a) | ((u32)f2bf(b) << 16);
}
__device__ __forceinline__ size_t cmrow(int g) {   // class-major row index
  return (size_t)(((g & 63) << 10) | (g >> 6));
}

__device__ __forceinline__ void gload_lds16(const void* src, void* dst) {
  __builtin_amdgcn_global_load_lds(
      (const __attribute__((address_space(1))) void*)src,
      (__attribute__((address_space(3))) void*)dst, 16, 0, 0);
}

#define PH_LDS 70912    // gj v3: Arow 16640 + G 16384 + Gfrag 16384 + Ml 20480 + PinvL 1024
#define DIST_LDS 66560  // B dbuf 2x32K + red

// ---------------------------------------------------------------------------
// Blocked Gauss-Jordan inverse v3, NB=16, 1024 threads (16 waves), MFMA
// update, 2 barriers/step. Wave w owns rows 16w..16w+15 in MFMA C-fragment
// layout (f32x4 x[ct]; elem (i,j): lane=j+16*(i>>2), reg=i&3).
// Per step: [A: own x[s] tile -> per-wave Ml tile; pivot wave -> Arow]
// bar1 [C': EVERY wave redundantly inverts the 16x16 pivot (readlane GJ,
// proven code); row-w broadcast via readlane; G row w + bf16 hi/lo Gfrag]
// bar2 [D: afr from own Ml tile (wave-ordered, no barrier); 2 MFMAs/tile].
// ---------------------------------------------------------------------------
__device__ void gj_body(const float* __restrict__ W, float* __restrict__ IW,
                        char* smem) {
  float (*Arow)[260]   = (float(*)[260])smem;                 // 16640 B
  float (*G)[256]      = (float(*)[256])(smem + 16640);       // 16384 B
  u16*  Gfrag          = (u16*)(smem + 33024);                // 16384 B
  float (*Ml)[16][20]  = (float(*)[16][20])(smem + 49408);    // 20480 B
  float (*PinvL)[16]   = (float(*)[16])(smem + 69888);        // 1024 B
  const int t = threadIdx.x, w = t >> 6, l = t & 63;
  const int lj = l & 15, lh = l >> 4;
  const int r0 = 16 * w;

  f32x4 x[16];
#pragma unroll
  for (int ct = 0; ct < 16; ++ct)
#pragma unroll
    for (int reg = 0; reg < 4; ++reg)
      x[ct][reg] = W[(size_t)(r0 + 4 * lh + reg) * D + 16 * ct + lj];

  for (int s = 0; s < 16; ++s) {
    // ---- Phase A: own x[s] tile -> Ml[w]; pivot wave stages Arow ----------
#pragma unroll
    for (int ct = 0; ct < 16; ++ct)
      if (ct == s)
#pragma unroll
        for (int reg = 0; reg < 4; ++reg)
          Ml[w][4 * lh + reg][lj] = x[ct][reg];
    if (w == s) {
#pragma unroll
      for (int ct = 0; ct < 16; ++ct)
#pragma unroll
        for (int reg = 0; reg < 4; ++reg)
          Arow[4 * lh + reg][16 * ct + lj] = x[ct][reg];
    }
    __syncthreads();   // bar1
    // ---- Phase C': redundant pivot-block inverse (every wave) -------------
    float p[16];
#pragma unroll
    for (int j = 0; j < 16; ++j) p[j] = 0.f;
    if (l < 16) {
      const float* ar = &Arow[l][16 * s];
      float4 rr0 = *(const float4*)(ar);
      float4 rr1 = *(const float4*)(ar + 4);
      float4 rr2 = *(const float4*)(ar + 8);
      float4 rr3 = *(const float4*)(ar + 12);
      p[0] = rr0.x; p[1] = rr0.y; p[2] = rr0.z; p[3] = rr0.w;
      p[4] = rr1.x; p[5] = rr1.y; p[6] = rr1.z; p[7] = rr1.w;
      p[8] = rr2.x; p[9] = rr2.y; p[10] = rr2.z; p[11] = rr2.w;
      p[12] = rr3.x; p[13] = rr3.y; p[14] = rr3.z; p[15] = rr3.w;
#pragma unroll
      for (int pp = 0; pp < 16; ++pp) {
        float u[16];
#pragma unroll
        for (int j = 0; j < 16; ++j)
          u[j] = __int_as_float(__builtin_amdgcn_readlane(__float_as_int(p[j]), pp));
        const float pv = u[pp];
        const float d = 1.0f / pv;
        if (l == pp) {
#pragma unroll
          for (int j = 0; j < 16; ++j) p[j] = u[j] * d;
          p[pp] = d;
        } else {
          const float md = p[pp] * d;
          u[pp] = pv + 1.0f;
#pragma unroll
          for (int j = 0; j < 16; ++j) p[j] = fmaf(-md, u[j], p[j]);
        }
      }
      if (w == s) {
#pragma unroll
        for (int j = 0; j < 16; ++j) PinvL[l][j] = p[j];
      }
    }
    // broadcast row w of Pinv to all lanes of wave w
    float pw[16];
#pragma unroll
    for (int q = 0; q < 16; ++q)
      pw[q] = __int_as_float(__builtin_amdgcn_readlane(__float_as_int(p[q]), w));
    // G row w = Pinv[w] * Arow  (C-columns hold I + Pinv)
    {
      const bool inC = ((l >> 2) == s);
      const int co = (l & 3) << 2;
      float4 g = make_float4(0.f, 0.f, 0.f, 0.f);
#pragma unroll
      for (int q = 0; q < 16; ++q) {
        const float4 av = *(const float4*)&Arow[q][4 * l];
        g.x = fmaf(pw[q], av.x, g.x); g.y = fmaf(pw[q], av.y, g.y);
        g.z = fmaf(pw[q], av.z, g.z); g.w = fmaf(pw[q], av.w, g.w);
      }
      if (inC) {
        g.x = pw[co + 0] + (w == co + 0 ? 1.f : 0.f);
        g.y = pw[co + 1] + (w == co + 1 ? 1.f : 0.f);
        g.z = pw[co + 2] + (w == co + 2 ? 1.f : 0.f);
        g.w = pw[co + 3] + (w == co + 3 ? 1.f : 0.f);
      }
      *(float4*)&G[w][4 * l] = g;
      const int e0 = w & 7;
      const int lbase = 16 * (w >> 3);
      const int gct = l >> 2;
      const float gv[4] = {g.x, g.y, g.z, g.w};
#pragma unroll
      for (int cc = 0; cc < 4; ++cc) {
        const int cl = 4 * (l & 3) + cc;
        const u16 hi = f2bf(gv[cc]);
        const u16 lo = f2bf(gv[cc] - bf2f(hi));
        Gfrag[(gct * 64 + lbase + cl) * 8 + e0] = hi;
        Gfrag[(gct * 64 + 32 + lbase + cl) * 8 + e0] = lo;
      }
    }
    __syncthreads();   // bar2
    // ---- Phase D: MFMA update / pivot-tile readback (no trailing barrier) -
    bfv8 afr;
    {
      float4 f0 = *(const float4*)&Ml[w][lj][8 * (lh & 1)];
      float4 f1 = *(const float4*)&Ml[w][lj][8 * (lh & 1) + 4];
      const float fv[8] = {f0.x, f0.y, f0.z, f0.w, f1.x, f1.y, f1.z, f1.w};
      union { bfv8 v; u16 e[8]; } A;
      if (lh < 2) {
#pragma unroll
        for (int e = 0; e < 8; ++e) A.e[e] = f2bf(-fv[e]);
      } else {
#pragma unroll
        for (int e = 0; e < 8; ++e) {
          const float hi = bf2f(f2bf(fv[e]));
          A.e[e] = f2bf(-(fv[e] - hi));
        }
      }
      afr = A.v;
    }
    if (w != s) {
#pragma unroll
      for (int ct = 0; ct < 16; ++ct) {
        bfv8 b1 = *(const bfv8*)&Gfrag[(ct * 64 + l) * 8];
        bfv8 b2 = *(const bfv8*)&Gfrag[(ct * 64 + (l ^ 32)) * 8];
        x[ct] = __builtin_amdgcn_mfma_f32_16x16x32_bf16(afr, b1, x[ct], 0, 0, 0);
        x[ct] = __builtin_amdgcn_mfma_f32_16x16x32_bf16(afr, b2, x[ct], 0, 0, 0);
      }
    } else {
#pragma unroll
      for (int ct = 0; ct < 16; ++ct) {
        if (ct == s) {
#pragma unroll
          for (int reg = 0; reg < 4; ++reg)
            x[ct][reg] = PinvL[4 * lh + reg][lj];
        } else {
#pragma unroll
          for (int reg = 0; reg < 4; ++reg)
            x[ct][reg] = G[4 * lh + reg][16 * ct + lj];
        }
      }
    }
  }
  __syncthreads();
#pragma unroll
  for (int ct = 0; ct < 16; ++ct)
#pragma unroll
    for (int reg = 0; reg < 4; ++reg)
      IW[(size_t)(r0 + 4 * lh + reg) * D + 16 * ct + lj] = x[ct][reg];
}

// ---------------------------------------------------------------------------
// prep body, 1024 threads (round-7 proven): 128 rows x FULL 256 cols x K256.
// ---------------------------------------------------------------------------
template <int MODE, bool WRITE_NRM>
__device__ void prep_body(const float* __restrict__ Ain,
                          const u16* __restrict__ Brows,
                          const float* __restrict__ biasv,
                          u16* __restrict__ Out, float* __restrict__ nrm,
                          float* __restrict__ nfp, int it, char* smem) {
  const int tx = threadIdx.x, ww = tx >> 6, l = tx & 63;
  const int mw = ww >> 3, nw = ww & 7, l4 = l >> 4, lm = l & 15;
  char* Ab = smem;
  float* nfpart = (float*)(smem + 65536);  // [8][128]

  bfv8 bfr[2][8];
#pragma unroll
  for (int nf2 = 0; nf2 < 2; ++nf2)
#pragma unroll
    for (int ks = 0; ks < 8; ++ks)
      bfr[nf2][ks] = *(const bfv8*)(Brows +
          (size_t)(nw * 32 + nf2 * 16 + lm) * D + ks * 32 + l4 * 8);

  {
    const int r = tx >> 3, sg = tx & 7;
    const float* arow = Ain + (size_t)(it * 128 + r) * D + sg * 32;
    float ss = 0.f;
#pragma unroll
    for (int g2 = 0; g2 < 4; ++g2) {
      float4 v0 = *(const float4*)(arow + g2 * 8);
      float4 v1 = *(const float4*)(arow + g2 * 8 + 4);
      ss = fmaf(v0.x, v0.x, fmaf(v0.y, v0.y, fmaf(v0.z, v0.z, fmaf(v0.w, v0.w, ss))));
      ss = fmaf(v1.x, v1.x, fmaf(v1.y, v1.y, fmaf(v1.z, v1.z, fmaf(v1.w, v1.w, ss))));
      uint4 w4;
      w4.x = pk2(v0.x, v0.y); w4.y = pk2(v0.z, v0.w);
      w4.z = pk2(v1.x, v1.y); w4.w = pk2(v1.z, v1.w);
      *(uint4*)(Ab + (sg * 8 + (r >> 4)) * 1024 + ((r & 15) + g2 * 16) * 16) = w4;
    }
    ss += __shfl_xor(ss, 1, 64);
    ss += __shfl_xor(ss, 2, 64);
    ss += __shfl_xor(ss, 4, 64);
    if (WRITE_NRM && sg == 0) nrm[cmrow(it * 128 + r)] = ss;
  }
  __syncthreads();

  const bfv8* A8 = (const bfv8*)Ab;
  f32x4 acc[4][2];
#pragma unroll
  for (int mf = 0; mf < 4; ++mf) {
    acc[mf][0] = f32x4{0.f, 0.f, 0.f, 0.f};
    acc[mf][1] = f32x4{0.f, 0.f, 0.f, 0.f};
  }
#pragma unroll
  for (int ks = 0; ks < 8; ++ks)
#pragma unroll
    for (int mf = 0; mf < 4; ++mf) {
      bfv8 a = A8[(ks * 8 + mw * 4 + mf) * 64 + l];
      acc[mf][0] = __builtin_amdgcn_mfma_f32_16x16x32_bf16(a, bfr[0][ks], acc[mf][0], 0, 0, 0);
      acc[mf][1] = __builtin_amdgcn_mfma_f32_16x16x32_bf16(a, bfr[1][ks], acc[mf][1], 0, 0, 0);
    }

  float bias[2];
  if (MODE == 0) {
#pragma unroll
    for (int nf2 = 0; nf2 < 2; ++nf2)
      bias[nf2] = biasv[nw * 32 + nf2 * 16 + lm];
  } else {
#pragma unroll
    for (int nf2 = 0; nf2 < 2; ++nf2) {
      float pd = 0.f;
#pragma unroll
      for (int ks = 0; ks < 8; ++ks) {
        float4 b0 = *(const float4*)(biasv + ks * 32 + l4 * 8);
        float4 b1 = *(const float4*)(biasv + ks * 32 + l4 * 8 + 4);
        pd = fmaf(b0.x, bf2f((u16)bfr[nf2][ks][0]), pd);
        pd = fmaf(b0.y, bf2f((u16)bfr[nf2][ks][1]), pd);
        pd = fmaf(b0.z, bf2f((u16)bfr[nf2][ks][2]), pd);
        pd = fmaf(b0.w, bf2f((u16)bfr[nf2][ks][3]), pd);
        pd = fmaf(b1.x, bf2f((u16)bfr[nf2][ks][4]), pd);
        pd = fmaf(b1.y, bf2f((u16)bfr[nf2][ks][5]), pd);
        pd = fmaf(b1.z, bf2f((u16)bfr[nf2][ks][6]), pd);
        pd = fmaf(b1.w, bf2f((u16)bfr[nf2][ks][7]), pd);
      }
      pd += __shfl_xor(pd, 16, 64);
      pd += __shfl_xor(pd, 32, 64);
      bias[nf2] = -pd;
    }
  }

#pragma unroll
  for (int mf = 0; mf < 4; ++mf)
#pragma unroll
    for (int rr = 0; rr < 4; ++rr) {
      const int g = it * 128 + mw * 64 + mf * 16 + l4 * 4 + rr;
      const size_t orow = cmrow(g) * D;
      float v2 = 0.f;
#pragma unroll
      for (int nf2 = 0; nf2 < 2; ++nf2) {
        const float v = acc[mf][nf2][rr] + bias[nf2];
        const u16 hv = f2bf(v);
        Out[orow + nw * 32 + nf2 * 16 + lm] = hv;
        const float vr = bf2f(hv);
        v2 = fmaf(vr, vr, v2);
      }
      v2 += __shfl_xor(v2, 1, 64);
      v2 += __shfl_xor(v2, 2, 64);
      v2 += __shfl_xor(v2, 4, 64);
      v2 += __shfl_xor(v2, 8, 64);
      if (lm == 0) nfpart[nw * 128 + mw * 64 + mf * 16 + l4 * 4 + rr] = v2;
    }
  __syncthreads();
  if (tx < 128) {
    float s = 0.f;
#pragma unroll
    for (int q = 0; q < 8; ++q) s += nfpart[q * 128 + tx];
    nfp[cmrow(it * 128 + tx)] = s;
  }
}

// n2 norms role: 32 blocks x 1024 thr, 2048 rows each, class-major write
__device__ void norms_role(const float* __restrict__ p2, float* __restrict__ n2,
                           int idx) {
  const int tx = threadIdx.x, q = tx & 3;
#pragma unroll
  for (int rep = 0; rep < 8; ++rep) {
    const int g = idx * 2048 + rep * 256 + (tx >> 2);
    const float* row = p2 + (size_t)g * D + q * 64;
    float ss = 0.f;
#pragma unroll
    for (int g2 = 0; g2 < 16; ++g2) {
      float4 v = *(const float4*)(row + g2 * 4);
      ss = fmaf(v.x, v.x, fmaf(v.y, v.y, fmaf(v.z, v.z, fmaf(v.w, v.w, ss))));
    }
    ss += __shfl_xor(ss, 1, 64);
    ss += __shfl_xor(ss, 2, 64);
    if (q == 0) n2[cmrow(g)] = ss;
  }
}

// phase1: block 0 = gj inverse; 1..512 = prep<0> (F); 513..544 = n2 norms
__global__ __launch_bounds__(1024, 1) void phase1_kernel(
    const float* __restrict__ p1, const float* __restrict__ p2,
    const float* __restrict__ W, const u16* __restrict__ Wb,
    const float* __restrict__ bv, u16* __restrict__ Fb,
    float* __restrict__ n1, float* __restrict__ n2,
    float* __restrict__ nf, float* __restrict__ IWa) {
  extern __shared__ char smem[];
  const int b = blockIdx.x;
  if (b == 0) {
    gj_body(W, IWa, smem);
  } else if (b <= 512) {
    prep_body<0, true>(p1, Wb, bv, Fb, n1, nf, b - 1, smem);
  } else {
    norms_role(p2, n2, b - 513);
  }
}

// phase3: prep<1> (Q = (p2-b)@IW^T via bias fold)
__global__ __launch_bounds__(1024, 1) void phase3_kernel(
    const float* __restrict__ p2, const u16* __restrict__ IWb,
    const float* __restrict__ bv, u16* __restrict__ Qb,
    float* __restrict__ nq) {
  extern __shared__ char smem[];
  prep_body<1, false>(p2, IWb, bv, Qb, nullptr, nq, blockIdx.x, smem);
}

__global__ __launch_bounds__(256) void nr_mult_bf16(const float* __restrict__ X,
                                                    const float* __restrict__ R,
                                                    u16* __restrict__ Yb) {
  __shared__ float xrow[D];
  const int i = blockIdx.x, j = threadIdx.x;
  xrow[j] = X[i * D + j];
  __syncthreads();
  float acc = 0.f;
#pragma unroll 8
  for (int k = 0; k < D; ++k) acc = fmaf(xrow[k], R[k * D + j], acc);
  Yb[i * D + j] = f2bf(acc);
}

__global__ __launch_bounds__(256) void wconv(const float* __restrict__ W,
                                             u16* __restrict__ Wb) {
  const int i = blockIdx.x * 256 + threadIdx.x;
  Wb[i] = f2bf(W[i]);
}

// ---------------------------------------------------------------------------
// dist body (proven): 256 thr, one direction, 512 blocks (c x i-tile).
// A-fragments in registers (wave = 32 rows x 128 cols), B dbuf LDS 2x32KB.
// ---------------------------------------------------------------------------
template <int DIR>
__device__ void dist_body(const float* __restrict__ Ain,
                          const u16* __restrict__ Bin,
                          const float* __restrict__ nA,
                          const float* __restrict__ nB,
                          float* __restrict__ partial, int bid, char* smem) {
  const int lb = (bid & 7) * 64 + (bid >> 3);   // XCD-chunked swizzle (512=8x64)
  const int c = lb >> 3, it = lb & 7;
  const int tx = threadIdx.x, wid = tx >> 6, l = tx & 63;
  const int l4 = l >> 4, lm = l & 15;

  auto issue_b = [&](int half, int jt) {
    const size_t base = ((size_t)(c << 10) + jt * 128) * D;
#pragma unroll
    for (int jf = 0; jf < 8; ++jf) {
      const u16* src = Bin + base + (size_t)(jf * 16 + lm) * D
                       + half * 128 + wid * 32 + l4 * 8;
      gload_lds16(src, smem + half * 32768 + (wid * 8 + jf) * 1024);
    }
  };

  issue_b(0, 0);
  bfv8 afr[2][8];
  const float* abase = Ain + ((size_t)(it * 128 + wid * 32) * NC + c) * D;
#pragma unroll
  for (int m = 0; m < 2; ++m)
#pragma unroll
    for (int ks = 0; ks < 8; ++ks) {
      const float* ap = abase + (size_t)(m * 16 + lm) * (NC * D) + ks * 32 + l4 * 8;
      float4 v0 = *(const float4*)(ap);
      float4 v1 = *(const float4*)(ap + 4);
      union { bfv8 v; uint4 u; } cv;
      cv.u.x = pk2(v0.x, v0.y); cv.u.y = pk2(v0.z, v0.w);
      cv.u.z = pk2(v1.x, v1.y); cv.u.w = pk2(v1.z, v1.w);
      afr[m][ks] = cv.v;
    }
  float na[2][4];
#pragma unroll
  for (int m = 0; m < 2; ++m)
#pragma unroll
    for (int rr = 0; rr < 4; ++rr)
      na[m][rr] = nA[(c << 10) + it * 128 + wid * 32 + m * 16 + l4 * 4 + rr];
  float minv[2][4];
#pragma unroll
  for (int m = 0; m < 2; ++m)
#pragma unroll
    for (int rr = 0; rr < 4; ++rr) minv[m][rr] = 3.0e38f;
  __syncthreads();

  const bfv8* lds8 = (const bfv8*)smem;
  for (int jt = 0; jt < 8; ++jt) {
    f32x4 acc[2][8];
#pragma unroll
    for (int m = 0; m < 2; ++m)
#pragma unroll
      for (int n = 0; n < 8; ++n) acc[m][n] = f32x4{0.f, 0.f, 0.f, 0.f};
    float nbv[8];
#pragma unroll
    for (int n = 0; n < 8; ++n)
      nbv[n] = nB[(c << 10) + jt * 128 + n * 16 + lm];
    issue_b(1, jt);
#pragma unroll
    for (int ks = 0; ks < 4; ++ks) {
      bfv8 bb[8];
#pragma unroll
      for (int n = 0; n < 8; ++n) bb[n] = lds8[(ks * 8 + n) * 64 + l];
#pragma unroll
      for (int m = 0; m < 2; ++m)
#pragma unroll
        for (int n = 0; n < 8; ++n)
          acc[m][n] = __builtin_amdgcn_mfma_f32_16x16x32_bf16(afr[m][ks], bb[n], acc[m][n], 0, 0, 0);
    }
    __syncthreads();
    if (jt < 7) issue_b(0, jt + 1);
#pragma unroll
    for (int ks = 4; ks < 8; ++ks) {
      bfv8 bb[8];
#pragma unroll
      for (int n = 0; n < 8; ++n) bb[n] = lds8[2048 + ((ks - 4) * 8 + n) * 64 + l];
#pragma unroll
      for (int m = 0; m < 2; ++m)
#pragma unroll
        for (int n = 0; n < 8; ++n)
          acc[m][n] = __builtin_amdgcn_mfma_f32_16x16x32_bf16(afr[m][ks], bb[n], acc[m][n], 0, 0, 0);
    }
#pragma unroll
    for (int m = 0; m < 2; ++m)
#pragma unroll
      for (int n = 0; n < 8; ++n)
#pragma unroll
        for (int rr = 0; rr < 4; ++rr) {
          const float dd = na[m][rr] + nbv[n] - 2.0f * acc[m][n][rr];
          minv[m][rr] = fminf(minv[m][rr], dd);
        }
    __syncthreads();
  }
  float* red = (float*)(smem + 65536);
#pragma unroll
  for (int m = 0; m < 2; ++m)
#pragma unroll
    for (int rr = 0; rr < 4; ++rr) {
      float mm = minv[m][rr];
      mm = fminf(mm, __shfl_xor(mm, 1, 64));
      mm = fminf(mm, __shfl_xor(mm, 2, 64));
      mm = fminf(mm, __shfl_xor(mm, 4, 64));
      mm = fminf(mm, __shfl_xor(mm, 8, 64));
      if (lm == 0) red[wid * 32 + m * 16 + l4 * 4 + rr] = mm;
    }
  __syncthreads();
  if (tx < 128) {
    float v = red[tx];
#pragma unroll
    for (int off = 32; off; off >>= 1) v += __shfl_xor(v, off, 64);
    if ((tx & 63) == 0) red[128 + (tx >> 6)] = v;
  }
  __syncthreads();
  if (tx == 0) partial[(c << 4) | (DIR << 3) | it] = red[128] + red[129];
}

// phase2: blocks 0..511 = dist dir=1 (p2 vs F); 512..767 = nr_residual
__global__ __launch_bounds__(256, 2) void phase2_kernel(
    const float* __restrict__ p2, const u16* __restrict__ Fb,
    const float* __restrict__ n2, const float* __restrict__ nf,
    const float* __restrict__ W, const float* __restrict__ IWa,
    float* __restrict__ Rt, float* __restrict__ partial) {
  extern __shared__ char smem[];
  const int b = blockIdx.x;
  if (b < 512) {
    dist_body<1>(p2, Fb, n2, nf, partial, b, smem);
  } else {
    float* wrow = (float*)smem;
    const int i = b - 512, j = threadIdx.x;
    wrow[j] = W[i * D + j];
    __syncthreads();
    float acc = 0.f;
#pragma unroll 8
    for (int k = 0; k < D; ++k) acc = fmaf(wrow[k], IWa[k * D + j], acc);
    Rt[i * D + j] = (i == j ? 2.0f : 0.0f) - acc;
  }
}

// dist0: dir=0 (p1 vs Q), 512 blocks
__global__ __launch_bounds__(256, 2) void dist0_kernel(
    const float* __restrict__ p1, const u16* __restrict__ Qb,
    const float* __restrict__ n1, const float* __restrict__ nq,
    float* __restrict__ partial) {
  extern __shared__ char smem[];
  dist_body<0>(p1, Qb, n1, nq, partial, blockIdx.x, smem);
}

__global__ void finalize_kernel(const float* __restrict__ partial,
                                float* __restrict__ out) {
  const int tx = threadIdx.x;
  if (tx >= 128) return;
  const int dir = tx >> 6, c = tx & 63;
  float s = 0.f;
#pragma unroll
  for (int it = 0; it < 8; ++it) s += partial[(c << 4) | (dir << 3) | it];
  out[dir * 64 + c] = s * (1.0f / 1024.0f);
}

extern "C" void kernel_launch(void* const* d_in, const int* in_sizes, int n_in,
                              void* d_out, int out_size, void* d_ws, size_t ws_size,
                              hipStream_t stream) {
  const float* p1 = (const float*)d_in[0];
  const float* p2 = (const float*)d_in[1];
  const float* W  = (const float*)d_in[2];
  const float* bv = (const float*)d_in[3];
  float* out = (float*)d_out;
  char* ws = (char*)d_ws;
  float* n1   = (float*)(ws);                    // 256KB
  float* n2   = (float*)(ws + (256 << 10));      // 256KB
  float* nf   = (float*)(ws + (512 << 10));      // 256KB
  float* nq   = (float*)(ws + (768 << 10));      // 256KB
  float* partial = (float*)(ws + (1024 << 10));  // 4KB
  u16* Wb  = (u16*)(ws + (1032 << 10));          // 128KB
  u16* IWb = (u16*)(ws + (1160 << 10));          // 128KB
  float* IWa = (float*)(ws + (1288 << 10));      // 256KB
  float* Rt  = (float*)(ws + (1544 << 10));      // 256KB
  u16* Fb  = (u16*)(ws + (2048 << 10));                   // 32MB
  u16* Qb  = (u16*)(ws + (2048 << 10) + (32u << 20));     // 32MB

  hipFuncSetAttribute((const void*)phase1_kernel,
                      hipFuncAttributeMaxDynamicSharedMemorySize, PH_LDS);
  hipFuncSetAttribute((const void*)phase2_kernel,
                      hipFuncAttributeMaxDynamicSharedMemorySize, DIST_LDS);
  hipFuncSetAttribute((const void*)phase3_kernel,
                      hipFuncAttributeMaxDynamicSharedMemorySize, PH_LDS);
  hipFuncSetAttribute((const void*)dist0_kernel,
                      hipFuncAttributeMaxDynamicSharedMemorySize, DIST_LDS);

  wconv<<<256, 256, 0, stream>>>(W, Wb);
  // gj v3 (block 0) || F-prep (512 blocks) || n2 norms
  phase1_kernel<<<545, 1024, PH_LDS, stream>>>(p1, p2, W, Wb, bv, Fb,
                                               n1, n2, nf, IWa);
  // dist dir=1 (needs only F) || NS residual (needs only IWa)
  phase2_kernel<<<768, 256, DIST_LDS, stream>>>(p2, Fb, n2, nf, W, IWa,
                                                Rt, partial);
  nr_mult_bf16<<<256, 256, 0, stream>>>(IWa, Rt, IWb);
  phase3_kernel<<<512, 1024, PH_LDS, stream>>>(p2, IWb, bv, Qb, nq);
  dist0_kernel<<<512, 256, DIST_LDS, stream>>>(p1, Qb, n1, nq, partial);
  finalize_kernel<<<1, 128, 0, stream>>>(partial, out);
}

// Round 9
// 297.618 us; speedup vs baseline: 1.1649x; 1.1649x over previous
//
#include <hip/hip_runtime.h>

#define D 256
#define NC 64

using u16 = unsigned short;
using u32 = unsigned int;

typedef __attribute__((ext_vector_type(8))) short bfv8;   // 8 bf16 = 16 B
typedef __attribute__((ext_vector_type(4))) float f32x4;
typedef __attribute__((ext_vector_type(2))) int v2i;

__device__ __forceinline__ float bf2f(u32 u) {
  union { u32 i; float f; } v; v.i = u << 16; return v.f;
}
__device__ __forceinline__ u16 f2bf(float f) {
  union { float f; u32 i; } v; v.f = f;
  u32 x = v.i;
  return (u16)((x + 0x7FFFu + ((x >> 16) & 1u)) >> 16);  // RTNE
}
__device__ __forceinline__ u32 pk2(float a, float b) {
  return (u32)f2bf(a) | ((u32)f2bf(b) << 16);
}
__device__ __forceinline__ size_t cmrow(int g) {   // class-major row index
  return (size_t)(((g & 63) << 10) | (g >> 6));
}

__device__ __forceinline__ void gload_lds16(const void* src, void* dst) {
  __builtin_amdgcn_global_load_lds(
      (const __attribute__((address_space(1))) void*)src,
      (__attribute__((address_space(3))) void*)dst, 16, 0, 0);
}

#define PH_LDS 71168    // gj: Ml 20480 + Arow 16384 + G 16384 + Gfrag 16640 + Pinv 1280
#define DIST_LDS 66560  // B dbuf 2x32K + red

// ---------------------------------------------------------------------------
// Blocked Gauss-Jordan inverse (round-7 proven 4-barrier body + 3 fixes),
// NB=16, 1024 threads (16 waves), MFMA update. Wave w owns rows 16w..16w+15
// in MFMA C-fragment layout (f32x4 x[ct]; elem (i,j): lane=j+16*(i>>2),
// reg=i&3). Fixes vs round 7: (1) Gfrag tile stride 520 u16 (8-way instead
// of 16-way write conflicts, reads stay clean); (2) Phase-D b2 built via
// permlane32_swap (VALU) instead of a second ds_read_b128; (3) afr hoisted
// before bar1.
// ---------------------------------------------------------------------------
__device__ void gj_body(const float* __restrict__ W, float* __restrict__ IW,
                        char* smem) {
  float (*Ml)[20]    = (float(*)[20])smem;                 // 256x20 = 20480 B
  float (*Arow)[256] = (float(*)[256])(smem + 20480);      // 16384 B
  float (*G)[256]    = (float(*)[256])(smem + 36864);      // 16384 B
  u16*  Gfrag        = (u16*)(smem + 53248);               // 16x520 u16 = 16640 B
  float (*Pinv)[20]  = (float(*)[20])(smem + 69888);       // 1280 B
  const int t = threadIdx.x, w = t >> 6, l = t & 63;
  const int lj = l & 15, lh = l >> 4;
  const int r0 = 16 * w;
  const bool lo32 = (l < 32);

  f32x4 x[16];
#pragma unroll
  for (int ct = 0; ct < 16; ++ct)
#pragma unroll
    for (int reg = 0; reg < 4; ++reg)
      x[ct][reg] = W[(size_t)(r0 + 4 * lh + reg) * D + 16 * ct + lj];

  for (int s = 0; s < 16; ++s) {
    // ---- Phase A: stage panel col-tile; pivot wave stages its rows --------
#pragma unroll
    for (int ct = 0; ct < 16; ++ct)
      if (ct == s)
#pragma unroll
        for (int reg = 0; reg < 4; ++reg)
          Ml[r0 + 4 * lh + reg][lj] = x[ct][reg];
    if (w == s) {
#pragma unroll
      for (int ct = 0; ct < 16; ++ct)
#pragma unroll
        for (int reg = 0; reg < 4; ++reg)
          Arow[4 * lh + reg][16 * ct + lj] = x[ct][reg];
    }
    // afr early: reads only own-wave Ml rows written above (wave-ordered)
    bfv8 afr;
    {
      const int row = r0 + lj;
      float4 f0 = *(const float4*)&Ml[row][8 * (lh & 1)];
      float4 f1 = *(const float4*)&Ml[row][8 * (lh & 1) + 4];
      const float fv[8] = {f0.x, f0.y, f0.z, f0.w, f1.x, f1.y, f1.z, f1.w};
      union { bfv8 v; u16 e[8]; } A;
      if (lh < 2) {
#pragma unroll
        for (int e = 0; e < 8; ++e) A.e[e] = f2bf(-fv[e]);
      } else {
#pragma unroll
        for (int e = 0; e < 8; ++e) {
          const float hi = bf2f(f2bf(fv[e]));
          A.e[e] = f2bf(-(fv[e] - hi));
        }
      }
      afr = A.v;
    }
    __syncthreads();   // bar1
    // ---- Phase B: serial 16x16 pivot-block inverse (wave 0, proven) -------
    if (t < 16) {
      float p[16];
      {
        float4 rr0 = *(const float4*)&Ml[16 * s + t][0];
        float4 rr1 = *(const float4*)&Ml[16 * s + t][4];
        float4 rr2 = *(const float4*)&Ml[16 * s + t][8];
        float4 rr3 = *(const float4*)&Ml[16 * s + t][12];
        p[0] = rr0.x; p[1] = rr0.y; p[2] = rr0.z; p[3] = rr0.w;
        p[4] = rr1.x; p[5] = rr1.y; p[6] = rr1.z; p[7] = rr1.w;
        p[8] = rr2.x; p[9] = rr2.y; p[10] = rr2.z; p[11] = rr2.w;
        p[12] = rr3.x; p[13] = rr3.y; p[14] = rr3.z; p[15] = rr3.w;
      }
#pragma unroll
      for (int pp = 0; pp < 16; ++pp) {
        float u[16];
#pragma unroll
        for (int j = 0; j < 16; ++j)
          u[j] = __int_as_float(__builtin_amdgcn_readlane(__float_as_int(p[j]), pp));
        const float pv = u[pp];
        const float d = 1.0f / pv;
        if (t == pp) {
#pragma unroll
          for (int j = 0; j < 16; ++j) p[j] = u[j] * d;
          p[pp] = d;
        } else {
          const float md = p[pp] * d;
          u[pp] = pv + 1.0f;
#pragma unroll
          for (int j = 0; j < 16; ++j) p[j] = fmaf(-md, u[j], p[j]);
        }
      }
#pragma unroll
      for (int j = 0; j < 16; ++j) Pinv[t][j] = p[j];
    }
    __syncthreads();   // bar2
    // ---- Phase C: G row w = Pinv[w]*Arow + bf16 hi/lo frag-ordered copy ---
    {
      const bool inC = ((l >> 2) == s);
      const int co = (l & 3) << 2;
      const int gct = l >> 2;
      const int kk = w;
      float4 g = make_float4(0.f, 0.f, 0.f, 0.f);
#pragma unroll
      for (int q = 0; q < 16; ++q) {
        const float pv = Pinv[kk][q];
        const float4 av = *(const float4*)&Arow[q][4 * l];
        g.x = fmaf(pv, av.x, g.x); g.y = fmaf(pv, av.y, g.y);
        g.z = fmaf(pv, av.z, g.z); g.w = fmaf(pv, av.w, g.w);
      }
      if (inC) {
        g.x = Pinv[kk][co + 0] + (kk == co + 0 ? 1.f : 0.f);
        g.y = Pinv[kk][co + 1] + (kk == co + 1 ? 1.f : 0.f);
        g.z = Pinv[kk][co + 2] + (kk == co + 2 ? 1.f : 0.f);
        g.w = Pinv[kk][co + 3] + (kk == co + 3 ? 1.f : 0.f);
      }
      *(float4*)&G[kk][4 * l] = g;
      const int e0 = kk & 7;
      const int lbase = 16 * (kk >> 3);
      const float gv[4] = {g.x, g.y, g.z, g.w};
#pragma unroll
      for (int cc = 0; cc < 4; ++cc) {
        const int cl = 4 * (l & 3) + cc;
        const u16 hi = f2bf(gv[cc]);
        const u16 lo = f2bf(gv[cc] - bf2f(hi));
        Gfrag[gct * 520 + (lbase + cl) * 8 + e0] = hi;
        Gfrag[gct * 520 + (32 + lbase + cl) * 8 + e0] = lo;
      }
    }
    __syncthreads();   // bar3
    // ---- Phase D: MFMA update / pivot-tile readback ------------------------
    if (w != s) {
#pragma unroll
      for (int ct = 0; ct < 16; ++ct) {
        union { bfv8 v; uint4 u; } B1, B2;
        B1.v = *(const bfv8*)&Gfrag[ct * 520 + l * 8];
#if __has_builtin(__builtin_amdgcn_permlane32_swap)
        {
          v2i r;
          r = __builtin_amdgcn_permlane32_swap((int)B1.u.x, (int)B1.u.x, false, false);
          B2.u.x = lo32 ? (u32)r.y : (u32)r.x;
          r = __builtin_amdgcn_permlane32_swap((int)B1.u.y, (int)B1.u.y, false, false);
          B2.u.y = lo32 ? (u32)r.y : (u32)r.x;
          r = __builtin_amdgcn_permlane32_swap((int)B1.u.z, (int)B1.u.z, false, false);
          B2.u.z = lo32 ? (u32)r.y : (u32)r.x;
          r = __builtin_amdgcn_permlane32_swap((int)B1.u.w, (int)B1.u.w, false, false);
          B2.u.w = lo32 ? (u32)r.y : (u32)r.x;
        }
#else
        B2.v = *(const bfv8*)&Gfrag[ct * 520 + (l ^ 32) * 8];
#endif
        x[ct] = __builtin_amdgcn_mfma_f32_16x16x32_bf16(afr, B1.v, x[ct], 0, 0, 0);
        x[ct] = __builtin_amdgcn_mfma_f32_16x16x32_bf16(afr, B2.v, x[ct], 0, 0, 0);
      }
    } else {
#pragma unroll
      for (int ct = 0; ct < 16; ++ct) {
        if (ct == s) {
#pragma unroll
          for (int reg = 0; reg < 4; ++reg)
            x[ct][reg] = Pinv[4 * lh + reg][lj];
        } else {
#pragma unroll
          for (int reg = 0; reg < 4; ++reg)
            x[ct][reg] = G[4 * lh + reg][16 * ct + lj];
        }
      }
    }
    __syncthreads();   // bar4
  }
#pragma unroll
  for (int ct = 0; ct < 16; ++ct)
#pragma unroll
    for (int reg = 0; reg < 4; ++reg)
      IW[(size_t)(r0 + 4 * lh + reg) * D + 16 * ct + lj] = x[ct][reg];
}

// ---------------------------------------------------------------------------
// prep body, 1024 threads (round-7 proven): 128 rows x FULL 256 cols x K256.
// ---------------------------------------------------------------------------
template <int MODE, bool WRITE_NRM>
__device__ void prep_body(const float* __restrict__ Ain,
                          const u16* __restrict__ Brows,
                          const float* __restrict__ biasv,
                          u16* __restrict__ Out, float* __restrict__ nrm,
                          float* __restrict__ nfp, int it, char* smem) {
  const int tx = threadIdx.x, ww = tx >> 6, l = tx & 63;
  const int mw = ww >> 3, nw = ww & 7, l4 = l >> 4, lm = l & 15;
  char* Ab = smem;
  float* nfpart = (float*)(smem + 65536);  // [8][128]

  bfv8 bfr[2][8];
#pragma unroll
  for (int nf2 = 0; nf2 < 2; ++nf2)
#pragma unroll
    for (int ks = 0; ks < 8; ++ks)
      bfr[nf2][ks] = *(const bfv8*)(Brows +
          (size_t)(nw * 32 + nf2 * 16 + lm) * D + ks * 32 + l4 * 8);

  {
    const int r = tx >> 3, sg = tx & 7;
    const float* arow = Ain + (size_t)(it * 128 + r) * D + sg * 32;
    float ss = 0.f;
#pragma unroll
    for (int g2 = 0; g2 < 4; ++g2) {
      float4 v0 = *(const float4*)(arow + g2 * 8);
      float4 v1 = *(const float4*)(arow + g2 * 8 + 4);
      ss = fmaf(v0.x, v0.x, fmaf(v0.y, v0.y, fmaf(v0.z, v0.z, fmaf(v0.w, v0.w, ss))));
      ss = fmaf(v1.x, v1.x, fmaf(v1.y, v1.y, fmaf(v1.z, v1.z, fmaf(v1.w, v1.w, ss))));
      uint4 w4;
      w4.x = pk2(v0.x, v0.y); w4.y = pk2(v0.z, v0.w);
      w4.z = pk2(v1.x, v1.y); w4.w = pk2(v1.z, v1.w);
      *(uint4*)(Ab + (sg * 8 + (r >> 4)) * 1024 + ((r & 15) + g2 * 16) * 16) = w4;
    }
    ss += __shfl_xor(ss, 1, 64);
    ss += __shfl_xor(ss, 2, 64);
    ss += __shfl_xor(ss, 4, 64);
    if (WRITE_NRM && sg == 0) nrm[cmrow(it * 128 + r)] = ss;
  }
  __syncthreads();

  const bfv8* A8 = (const bfv8*)Ab;
  f32x4 acc[4][2];
#pragma unroll
  for (int mf = 0; mf < 4; ++mf) {
    acc[mf][0] = f32x4{0.f, 0.f, 0.f, 0.f};
    acc[mf][1] = f32x4{0.f, 0.f, 0.f, 0.f};
  }
#pragma unroll
  for (int ks = 0; ks < 8; ++ks)
#pragma unroll
    for (int mf = 0; mf < 4; ++mf) {
      bfv8 a = A8[(ks * 8 + mw * 4 + mf) * 64 + l];
      acc[mf][0] = __builtin_amdgcn_mfma_f32_16x16x32_bf16(a, bfr[0][ks], acc[mf][0], 0, 0, 0);
      acc[mf][1] = __builtin_amdgcn_mfma_f32_16x16x32_bf16(a, bfr[1][ks], acc[mf][1], 0, 0, 0);
    }

  float bias[2];
  if (MODE == 0) {
#pragma unroll
    for (int nf2 = 0; nf2 < 2; ++nf2)
      bias[nf2] = biasv[nw * 32 + nf2 * 16 + lm];
  } else {
#pragma unroll
    for (int nf2 = 0; nf2 < 2; ++nf2) {
      float pd = 0.f;
#pragma unroll
      for (int ks = 0; ks < 8; ++ks) {
        float4 b0 = *(const float4*)(biasv + ks * 32 + l4 * 8);
        float4 b1 = *(const float4*)(biasv + ks * 32 + l4 * 8 + 4);
        pd = fmaf(b0.x, bf2f((u16)bfr[nf2][ks][0]), pd);
        pd = fmaf(b0.y, bf2f((u16)bfr[nf2][ks][1]), pd);
        pd = fmaf(b0.z, bf2f((u16)bfr[nf2][ks][2]), pd);
        pd = fmaf(b0.w, bf2f((u16)bfr[nf2][ks][3]), pd);
        pd = fmaf(b1.x, bf2f((u16)bfr[nf2][ks][4]), pd);
        pd = fmaf(b1.y, bf2f((u16)bfr[nf2][ks][5]), pd);
        pd = fmaf(b1.z, bf2f((u16)bfr[nf2][ks][6]), pd);
        pd = fmaf(b1.w, bf2f((u16)bfr[nf2][ks][7]), pd);
      }
      pd += __shfl_xor(pd, 16, 64);
      pd += __shfl_xor(pd, 32, 64);
      bias[nf2] = -pd;
    }
  }

#pragma unroll
  for (int mf = 0; mf < 4; ++mf)
#pragma unroll
    for (int rr = 0; rr < 4; ++rr) {
      const int g = it * 128 + mw * 64 + mf * 16 + l4 * 4 + rr;
      const size_t orow = cmrow(g) * D;
      float v2 = 0.f;
#pragma unroll
      for (int nf2 = 0; nf2 < 2; ++nf2) {
        const float v = acc[mf][nf2][rr] + bias[nf2];
        const u16 hv = f2bf(v);
        Out[orow + nw * 32 + nf2 * 16 + lm] = hv;
        const float vr = bf2f(hv);
        v2 = fmaf(vr, vr, v2);
      }
      v2 += __shfl_xor(v2, 1, 64);
      v2 += __shfl_xor(v2, 2, 64);
      v2 += __shfl_xor(v2, 4, 64);
      v2 += __shfl_xor(v2, 8, 64);
      if (lm == 0) nfpart[nw * 128 + mw * 64 + mf * 16 + l4 * 4 + rr] = v2;
    }
  __syncthreads();
  if (tx < 128) {
    float s = 0.f;
#pragma unroll
    for (int q = 0; q < 8; ++q) s += nfpart[q * 128 + tx];
    nfp[cmrow(it * 128 + tx)] = s;
  }
}

// n2 norms role: 32 blocks x 1024 thr, 2048 rows each, class-major write
__device__ void norms_role(const float* __restrict__ p2, float* __restrict__ n2,
                           int idx) {
  const int tx = threadIdx.x, q = tx & 3;
#pragma unroll
  for (int rep = 0; rep < 8; ++rep) {
    const int g = idx * 2048 + rep * 256 + (tx >> 2);
    const float* row = p2 + (size_t)g * D + q * 64;
    float ss = 0.f;
#pragma unroll
    for (int g2 = 0; g2 < 16; ++g2) {
      float4 v = *(const float4*)(row + g2 * 4);
      ss = fmaf(v.x, v.x, fmaf(v.y, v.y, fmaf(v.z, v.z, fmaf(v.w, v.w, ss))));
    }
    ss += __shfl_xor(ss, 1, 64);
    ss += __shfl_xor(ss, 2, 64);
    if (q == 0) n2[cmrow(g)] = ss;
  }
}

// phase1: block 0 = gj inverse; 1..512 = prep<0> (F); 513..544 = n2 norms
__global__ __launch_bounds__(1024, 1) void phase1_kernel(
    const float* __restrict__ p1, const float* __restrict__ p2,
    const float* __restrict__ W, const u16* __restrict__ Wb,
    const float* __restrict__ bv, u16* __restrict__ Fb,
    float* __restrict__ n1, float* __restrict__ n2,
    float* __restrict__ nf, float* __restrict__ IWa) {
  extern __shared__ char smem[];
  const int b = blockIdx.x;
  if (b == 0) {
    gj_body(W, IWa, smem);
  } else if (b <= 512) {
    prep_body<0, true>(p1, Wb, bv, Fb, n1, nf, b - 1, smem);
  } else {
    norms_role(p2, n2, b - 513);
  }
}

// phase3: prep<1> (Q = (p2-b)@IW^T via bias fold)
__global__ __launch_bounds__(1024, 1) void phase3_kernel(
    const float* __restrict__ p2, const u16* __restrict__ IWb,
    const float* __restrict__ bv, u16* __restrict__ Qb,
    float* __restrict__ nq) {
  extern __shared__ char smem[];
  prep_body<1, false>(p2, IWb, bv, Qb, nullptr, nq, blockIdx.x, smem);
}

__global__ __launch_bounds__(256) void nr_mult_bf16(const float* __restrict__ X,
                                                    const float* __restrict__ R,
                                                    u16* __restrict__ Yb) {
  __shared__ float xrow[D];
  const int i = blockIdx.x, j = threadIdx.x;
  xrow[j] = X[i * D + j];
  __syncthreads();
  float acc = 0.f;
#pragma unroll 8
  for (int k = 0; k < D; ++k) acc = fmaf(xrow[k], R[k * D + j], acc);
  Yb[i * D + j] = f2bf(acc);
}

__global__ __launch_bounds__(256) void wconv(const float* __restrict__ W,
                                             u16* __restrict__ Wb) {
  const int i = blockIdx.x * 256 + threadIdx.x;
  Wb[i] = f2bf(W[i]);
}

// ---------------------------------------------------------------------------
// dist body (proven): 256 thr, one direction, 512 blocks (c x i-tile).
// A-fragments in registers (wave = 32 rows x 128 cols), B dbuf LDS 2x32KB.
// ---------------------------------------------------------------------------
template <int DIR>
__device__ void dist_body(const float* __restrict__ Ain,
                          const u16* __restrict__ Bin,
                          const float* __restrict__ nA,
                          const float* __restrict__ nB,
                          float* __restrict__ partial, int bid, char* smem) {
  const int lb = (bid & 7) * 64 + (bid >> 3);   // XCD-chunked swizzle (512=8x64)
  const int c = lb >> 3, it = lb & 7;
  const int tx = threadIdx.x, wid = tx >> 6, l = tx & 63;
  const int l4 = l >> 4, lm = l & 15;

  auto issue_b = [&](int half, int jt) {
    const size_t base = ((size_t)(c << 10) + jt * 128) * D;
#pragma unroll
    for (int jf = 0; jf < 8; ++jf) {
      const u16* src = Bin + base + (size_t)(jf * 16 + lm) * D
                       + half * 128 + wid * 32 + l4 * 8;
      gload_lds16(src, smem + half * 32768 + (wid * 8 + jf) * 1024);
    }
  };

  issue_b(0, 0);
  bfv8 afr[2][8];
  const float* abase = Ain + ((size_t)(it * 128 + wid * 32) * NC + c) * D;
#pragma unroll
  for (int m = 0; m < 2; ++m)
#pragma unroll
    for (int ks = 0; ks < 8; ++ks) {
      const float* ap = abase + (size_t)(m * 16 + lm) * (NC * D) + ks * 32 + l4 * 8;
      float4 v0 = *(const float4*)(ap);
      float4 v1 = *(const float4*)(ap + 4);
      union { bfv8 v; uint4 u; } cv;
      cv.u.x = pk2(v0.x, v0.y); cv.u.y = pk2(v0.z, v0.w);
      cv.u.z = pk2(v1.x, v1.y); cv.u.w = pk2(v1.z, v1.w);
      afr[m][ks] = cv.v;
    }
  float na[2][4];
#pragma unroll
  for (int m = 0; m < 2; ++m)
#pragma unroll
    for (int rr = 0; rr < 4; ++rr)
      na[m][rr] = nA[(c << 10) + it * 128 + wid * 32 + m * 16 + l4 * 4 + rr];
  float minv[2][4];
#pragma unroll
  for (int m = 0; m < 2; ++m)
#pragma unroll
    for (int rr = 0; rr < 4; ++rr) minv[m][rr] = 3.0e38f;
  __syncthreads();

  const bfv8* lds8 = (const bfv8*)smem;
  for (int jt = 0; jt < 8; ++jt) {
    f32x4 acc[2][8];
#pragma unroll
    for (int m = 0; m < 2; ++m)
#pragma unroll
      for (int n = 0; n < 8; ++n) acc[m][n] = f32x4{0.f, 0.f, 0.f, 0.f};
    float nbv[8];
#pragma unroll
    for (int n = 0; n < 8; ++n)
      nbv[n] = nB[(c << 10) + jt * 128 + n * 16 + lm];
    issue_b(1, jt);
#pragma unroll
    for (int ks = 0; ks < 4; ++ks) {
      bfv8 bb[8];
#pragma unroll
      for (int n = 0; n < 8; ++n) bb[n] = lds8[(ks * 8 + n) * 64 + l];
#pragma unroll
      for (int m = 0; m < 2; ++m)
#pragma unroll
        for (int n = 0; n < 8; ++n)
          acc[m][n] = __builtin_amdgcn_mfma_f32_16x16x32_bf16(afr[m][ks], bb[n], acc[m][n], 0, 0, 0);
    }
    __syncthreads();
    if (jt < 7) issue_b(0, jt + 1);
#pragma unroll
    for (int ks = 4; ks < 8; ++ks) {
      bfv8 bb[8];
#pragma unroll
      for (int n = 0; n < 8; ++n) bb[n] = lds8[2048 + ((ks - 4) * 8 + n) * 64 + l];
#pragma unroll
      for (int m = 0; m < 2; ++m)
#pragma unroll
        for (int n = 0; n < 8; ++n)
          acc[m][n] = __builtin_amdgcn_mfma_f32_16x16x32_bf16(afr[m][ks], bb[n], acc[m][n], 0, 0, 0);
    }
#pragma unroll
    for (int m = 0; m < 2; ++m)
#pragma unroll
      for (int n = 0; n < 8; ++n)
#pragma unroll
        for (int rr = 0; rr < 4; ++rr) {
          const float dd = na[m][rr] + nbv[n] - 2.0f * acc[m][n][rr];
          minv[m][rr] = fminf(minv[m][rr], dd);
        }
    __syncthreads();
  }
  float* red = (float*)(smem + 65536);
#pragma unroll
  for (int m = 0; m < 2; ++m)
#pragma unroll
    for (int rr = 0; rr < 4; ++rr) {
      float mm = minv[m][rr];
      mm = fminf(mm, __shfl_xor(mm, 1, 64));
      mm = fminf(mm, __shfl_xor(mm, 2, 64));
      mm = fminf(mm, __shfl_xor(mm, 4, 64));
      mm = fminf(mm, __shfl_xor(mm, 8, 64));
      if (lm == 0) red[wid * 32 + m * 16 + l4 * 4 + rr] = mm;
    }
  __syncthreads();
  if (tx < 128) {
    float v = red[tx];
#pragma unroll
    for (int off = 32; off; off >>= 1) v += __shfl_xor(v, off, 64);
    if ((tx & 63) == 0) red[128 + (tx >> 6)] = v;
  }
  __syncthreads();
  if (tx == 0) partial[(c << 4) | (DIR << 3) | it] = red[128] + red[129];
}

// phase2: blocks 0..511 = dist dir=1 (p2 vs F); 512..767 = nr_residual
__global__ __launch_bounds__(256, 2) void phase2_kernel(
    const float* __restrict__ p2, const u16* __restrict__ Fb,
    const float* __restrict__ n2, const float* __restrict__ nf,
    const float* __restrict__ W, const float* __restrict__ IWa,
    float* __restrict__ Rt, float* __restrict__ partial) {
  extern __shared__ char smem[];
  const int b = blockIdx.x;
  if (b < 512) {
    dist_body<1>(p2, Fb, n2, nf, partial, b, smem);
  } else {
    float* wrow = (float*)smem;
    const int i = b - 512, j = threadIdx.x;
    wrow[j] = W[i * D + j];
    __syncthreads();
    float acc = 0.f;
#pragma unroll 8
    for (int k = 0; k < D; ++k) acc = fmaf(wrow[k], IWa[k * D + j], acc);
    Rt[i * D + j] = (i == j ? 2.0f : 0.0f) - acc;
  }
}

// dist0: dir=0 (p1 vs Q), 512 blocks
__global__ __launch_bounds__(256, 2) void dist0_kernel(
    const float* __restrict__ p1, const u16* __restrict__ Qb,
    const float* __restrict__ n1, const float* __restrict__ nq,
    float* __restrict__ partial) {
  extern __shared__ char smem[];
  dist_body<0>(p1, Qb, n1, nq, partial, blockIdx.x, smem);
}

__global__ void finalize_kernel(const float* __restrict__ partial,
                                float* __restrict__ out) {
  const int tx = threadIdx.x;
  if (tx >= 128) return;
  const int dir = tx >> 6, c = tx & 63;
  float s = 0.f;
#pragma unroll
  for (int it = 0; it < 8; ++it) s += partial[(c << 4) | (dir << 3) | it];
  out[dir * 64 + c] = s * (1.0f / 1024.0f);
}

extern "C" void kernel_launch(void* const* d_in, const int* in_sizes, int n_in,
                              void* d_out, int out_size, void* d_ws, size_t ws_size,
                              hipStream_t stream) {
  const float* p1 = (const float*)d_in[0];
  const float* p2 = (const float*)d_in[1];
  const float* W  = (const float*)d_in[2];
  const float* bv = (const float*)d_in[3];
  float* out = (float*)d_out;
  char* ws = (char*)d_ws;
  float* n1   = (float*)(ws);                    // 256KB
  float* n2   = (float*)(ws + (256 << 10));      // 256KB
  float* nf   = (float*)(ws + (512 << 10));      // 256KB
  float* nq   = (float*)(ws + (768 << 10));      // 256KB
  float* partial = (float*)(ws + (1024 << 10));  // 4KB
  u16* Wb  = (u16*)(ws + (1032 << 10));          // 128KB
  u16* IWb = (u16*)(ws + (1160 << 10));          // 128KB
  float* IWa = (float*)(ws + (1288 << 10));      // 256KB
  float* Rt  = (float*)(ws + (1544 << 10));      // 256KB
  u16* Fb  = (u16*)(ws + (2048 << 10));                   // 32MB
  u16* Qb  = (u16*)(ws + (2048 << 10) + (32u << 20));     // 32MB

  hipFuncSetAttribute((const void*)phase1_kernel,
                      hipFuncAttributeMaxDynamicSharedMemorySize, PH_LDS);
  hipFuncSetAttribute((const void*)phase2_kernel,
                      hipFuncAttributeMaxDynamicSharedMemorySize, DIST_LDS);
  hipFuncSetAttribute((const void*)phase3_kernel,
                      hipFuncAttributeMaxDynamicSharedMemorySize, PH_LDS);
  hipFuncSetAttribute((const void*)dist0_kernel,
                      hipFuncAttributeMaxDynamicSharedMemorySize, DIST_LDS);

  wconv<<<256, 256, 0, stream>>>(W, Wb);
  // gj (block 0) || F-prep (512 blocks) || n2 norms
  phase1_kernel<<<545, 1024, PH_LDS, stream>>>(p1, p2, W, Wb, bv, Fb,
                                               n1, n2, nf, IWa);
  // dist dir=1 (needs only F) || NS residual (needs only IWa)
  phase2_kernel<<<768, 256, DIST_LDS, stream>>>(p2, Fb, n2, nf, W, IWa,
                                                Rt, partial);
  nr_mult_bf16<<<256, 256, 0, stream>>>(IWa, Rt, IWb);
  phase3_kernel<<<512, 1024, PH_LDS, stream>>>(p2, IWb, bv, Qb, nq);
  dist0_kernel<<<512, 256, DIST_LDS, stream>>>(p1, Qb, n1, nq, partial);
  finalize_kernel<<<1, 128, 0, stream>>>(partial, out);
}

// Round 10
// 281.921 us; speedup vs baseline: 1.2298x; 1.0557x over previous
//
#include <hip/hip_runtime.h>

#define D 256
#define NC 64

using u16 = unsigned short;
using u32 = unsigned int;

typedef __attribute__((ext_vector_type(8))) short bfv8;   // 8 bf16 = 16 B
typedef __attribute__((ext_vector_type(4))) float f32x4;
typedef __attribute__((ext_vector_type(2))) int v2i;

__device__ __forceinline__ float bf2f(u32 u) {
  union { u32 i; float f; } v; v.i = u << 16; return v.f;
}
__device__ __forceinline__ u16 f2bf(float f) {
  union { float f; u32 i; } v; v.f = f;
  u32 x = v.i;
  return (u16)((x + 0x7FFFu + ((x >> 16) & 1u)) >> 16);  // RTNE
}
__device__ __forceinline__ u32 pk2(float a, float b) {
  return (u32)f2bf(a) | ((u32)f2bf(b) << 16);
}
__device__ __forceinline__ size_t cmrow(int g) {   // class-major row index
  return (size_t)(((g & 63) << 10) | (g >> 6));
}

__device__ __forceinline__ void gload_lds16(const void* src, void* dst) {
  __builtin_amdgcn_global_load_lds(
      (const __attribute__((address_space(1))) void*)src,
      (__attribute__((address_space(3))) void*)dst, 16, 0, 0);
}

#define GJ_LDS 71168
#define DISTP_LDS 135680  // tile 64K + panel dbuf 64K + nfpart/minbuf 4K + nA 512

// ---------------------------------------------------------------------------
// Blocked Gauss-Jordan inverse (round-9 proven body, unchanged).
// ---------------------------------------------------------------------------
__device__ void gj_body(const float* __restrict__ W, float* __restrict__ IW,
                        char* smem) {
  float (*Ml)[20]    = (float(*)[20])smem;                 // 20480 B
  float (*Arow)[256] = (float(*)[256])(smem + 20480);      // 16384 B
  float (*G)[256]    = (float(*)[256])(smem + 36864);      // 16384 B
  u16*  Gfrag        = (u16*)(smem + 53248);               // 16640 B
  float (*Pinv)[20]  = (float(*)[20])(smem + 69888);       // 1280 B
  const int t = threadIdx.x, w = t >> 6, l = t & 63;
  const int lj = l & 15, lh = l >> 4;
  const int r0 = 16 * w;
  const bool lo32 = (l < 32);

  f32x4 x[16];
#pragma unroll
  for (int ct = 0; ct < 16; ++ct)
#pragma unroll
    for (int reg = 0; reg < 4; ++reg)
      x[ct][reg] = W[(size_t)(r0 + 4 * lh + reg) * D + 16 * ct + lj];

  for (int s = 0; s < 16; ++s) {
#pragma unroll
    for (int ct = 0; ct < 16; ++ct)
      if (ct == s)
#pragma unroll
        for (int reg = 0; reg < 4; ++reg)
          Ml[r0 + 4 * lh + reg][lj] = x[ct][reg];
    if (w == s) {
#pragma unroll
      for (int ct = 0; ct < 16; ++ct)
#pragma unroll
        for (int reg = 0; reg < 4; ++reg)
          Arow[4 * lh + reg][16 * ct + lj] = x[ct][reg];
    }
    bfv8 afr;
    {
      const int row = r0 + lj;
      float4 f0 = *(const float4*)&Ml[row][8 * (lh & 1)];
      float4 f1 = *(const float4*)&Ml[row][8 * (lh & 1) + 4];
      const float fv[8] = {f0.x, f0.y, f0.z, f0.w, f1.x, f1.y, f1.z, f1.w};
      union { bfv8 v; u16 e[8]; } A;
      if (lh < 2) {
#pragma unroll
        for (int e = 0; e < 8; ++e) A.e[e] = f2bf(-fv[e]);
      } else {
#pragma unroll
        for (int e = 0; e < 8; ++e) {
          const float hi = bf2f(f2bf(fv[e]));
          A.e[e] = f2bf(-(fv[e] - hi));
        }
      }
      afr = A.v;
    }
    __syncthreads();
    if (t < 16) {
      float p[16];
      {
        float4 rr0 = *(const float4*)&Ml[16 * s + t][0];
        float4 rr1 = *(const float4*)&Ml[16 * s + t][4];
        float4 rr2 = *(const float4*)&Ml[16 * s + t][8];
        float4 rr3 = *(const float4*)&Ml[16 * s + t][12];
        p[0] = rr0.x; p[1] = rr0.y; p[2] = rr0.z; p[3] = rr0.w;
        p[4] = rr1.x; p[5] = rr1.y; p[6] = rr1.z; p[7] = rr1.w;
        p[8] = rr2.x; p[9] = rr2.y; p[10] = rr2.z; p[11] = rr2.w;
        p[12] = rr3.x; p[13] = rr3.y; p[14] = rr3.z; p[15] = rr3.w;
      }
#pragma unroll
      for (int pp = 0; pp < 16; ++pp) {
        float u[16];
#pragma unroll
        for (int j = 0; j < 16; ++j)
          u[j] = __int_as_float(__builtin_amdgcn_readlane(__float_as_int(p[j]), pp));
        const float pv = u[pp];
        const float d = 1.0f / pv;
        if (t == pp) {
#pragma unroll
          for (int j = 0; j < 16; ++j) p[j] = u[j] * d;
          p[pp] = d;
        } else {
          const float md = p[pp] * d;
          u[pp] = pv + 1.0f;
#pragma unroll
          for (int j = 0; j < 16; ++j) p[j] = fmaf(-md, u[j], p[j]);
        }
      }
#pragma unroll
      for (int j = 0; j < 16; ++j) Pinv[t][j] = p[j];
    }
    __syncthreads();
    {
      const bool inC = ((l >> 2) == s);
      const int co = (l & 3) << 2;
      const int gct = l >> 2;
      const int kk = w;
      float4 g = make_float4(0.f, 0.f, 0.f, 0.f);
#pragma unroll
      for (int q = 0; q < 16; ++q) {
        const float pv = Pinv[kk][q];
        const float4 av = *(const float4*)&Arow[q][4 * l];
        g.x = fmaf(pv, av.x, g.x); g.y = fmaf(pv, av.y, g.y);
        g.z = fmaf(pv, av.z, g.z); g.w = fmaf(pv, av.w, g.w);
      }
      if (inC) {
        g.x = Pinv[kk][co + 0] + (kk == co + 0 ? 1.f : 0.f);
        g.y = Pinv[kk][co + 1] + (kk == co + 1 ? 1.f : 0.f);
        g.z = Pinv[kk][co + 2] + (kk == co + 2 ? 1.f : 0.f);
        g.w = Pinv[kk][co + 3] + (kk == co + 3 ? 1.f : 0.f);
      }
      *(float4*)&G[kk][4 * l] = g;
      const int e0 = kk & 7;
      const int lbase = 16 * (kk >> 3);
      const float gv[4] = {g.x, g.y, g.z, g.w};
#pragma unroll
      for (int cc = 0; cc < 4; ++cc) {
        const int cl = 4 * (l & 3) + cc;
        const u16 hi = f2bf(gv[cc]);
        const u16 lo = f2bf(gv[cc] - bf2f(hi));
        Gfrag[gct * 520 + (lbase + cl) * 8 + e0] = hi;
        Gfrag[gct * 520 + (32 + lbase + cl) * 8 + e0] = lo;
      }
    }
    __syncthreads();
    if (w != s) {
#pragma unroll
      for (int ct = 0; ct < 16; ++ct) {
        union { bfv8 v; uint4 u; } B1, B2;
        B1.v = *(const bfv8*)&Gfrag[ct * 520 + l * 8];
#if __has_builtin(__builtin_amdgcn_permlane32_swap)
        {
          v2i r;
          r = __builtin_amdgcn_permlane32_swap((int)B1.u.x, (int)B1.u.x, false, false);
          B2.u.x = lo32 ? (u32)r.y : (u32)r.x;
          r = __builtin_amdgcn_permlane32_swap((int)B1.u.y, (int)B1.u.y, false, false);
          B2.u.y = lo32 ? (u32)r.y : (u32)r.x;
          r = __builtin_amdgcn_permlane32_swap((int)B1.u.z, (int)B1.u.z, false, false);
          B2.u.z = lo32 ? (u32)r.y : (u32)r.x;
          r = __builtin_amdgcn_permlane32_swap((int)B1.u.w, (int)B1.u.w, false, false);
          B2.u.w = lo32 ? (u32)r.y : (u32)r.x;
        }
#else
        B2.v = *(const bfv8*)&Gfrag[ct * 520 + (l ^ 32) * 8];
#endif
        x[ct] = __builtin_amdgcn_mfma_f32_16x16x32_bf16(afr, B1.v, x[ct], 0, 0, 0);
        x[ct] = __builtin_amdgcn_mfma_f32_16x16x32_bf16(afr, B2.v, x[ct], 0, 0, 0);
      }
    } else {
#pragma unroll
      for (int ct = 0; ct < 16; ++ct) {
        if (ct == s) {
#pragma unroll
          for (int reg = 0; reg < 4; ++reg)
            x[ct][reg] = Pinv[4 * lh + reg][lj];
        } else {
#pragma unroll
          for (int reg = 0; reg < 4; ++reg)
            x[ct][reg] = G[4 * lh + reg][16 * ct + lj];
        }
      }
    }
    __syncthreads();
  }
#pragma unroll
  for (int ct = 0; ct < 16; ++ct)
#pragma unroll
    for (int reg = 0; reg < 4; ++reg)
      IW[(size_t)(r0 + 4 * lh + reg) * D + 16 * ct + lj] = x[ct][reg];
}

// ---------------------------------------------------------------------------
// convnorm: f32 row-major -> bf16 class-major + exact f32 row norms.
// 1024 thr, 256 rows/block (4 threads per row).
// ---------------------------------------------------------------------------
__device__ void convnorm_role(const float* __restrict__ P, u16* __restrict__ Pb,
                              float* __restrict__ nrm, int blk) {
  const int tx = threadIdx.x;
  const int r = tx >> 2, q = tx & 3;
  const int g = blk * 256 + r;
  const float* src = P + (size_t)g * D + q * 64;
  u16* dst = Pb + cmrow(g) * D + q * 64;
  float ss = 0.f;
#pragma unroll
  for (int g4 = 0; g4 < 8; ++g4) {
    float4 v0 = *(const float4*)(src + g4 * 8);
    float4 v1 = *(const float4*)(src + g4 * 8 + 4);
    ss = fmaf(v0.x, v0.x, fmaf(v0.y, v0.y, fmaf(v0.z, v0.z, fmaf(v0.w, v0.w, ss))));
    ss = fmaf(v1.x, v1.x, fmaf(v1.y, v1.y, fmaf(v1.z, v1.z, fmaf(v1.w, v1.w, ss))));
    uint4 w4;
    w4.x = pk2(v0.x, v0.y); w4.y = pk2(v0.z, v0.w);
    w4.z = pk2(v1.x, v1.y); w4.w = pk2(v1.z, v1.w);
    *(uint4*)(dst + g4 * 8) = w4;
  }
  ss += __shfl_xor(ss, 1, 64);
  ss += __shfl_xor(ss, 2, 64);
  if (q == 0) nrm[cmrow(g)] = ss;
}

// ---------------------------------------------------------------------------
// distp: fused {tile prep + pairwise distance + min} per (class, j-tile).
// 1024 thr. MODE 0: tile = p1_rows @ Wb^T + bv (F, dir=1).
//           MODE 1: tile = p2_rows @ IWb^T - b@IWb^T (Q, dir=0).
// Then: loop 16 i-chunks of the class-c bf16 input panel (dbuf LDS),
// MFMA(tile, panel) -> dist = nB + nA - 2dot -> per-i min over 128 j -> pmin.
// ---------------------------------------------------------------------------
template <int MODE>
__device__ void distp_body(const float* __restrict__ Pj,
                           const u16* __restrict__ Brows,
                           const float* __restrict__ biasv,
                           const u16* __restrict__ Pib,
                           const float* __restrict__ nB,
                           float* __restrict__ pmind, int bid, char* smem) {
  const int lb = (bid & 7) * 64 + (bid >> 3);   // XCD swizzle: class->XCD
  const int c = lb >> 3, jt = lb & 7;
  const int tx = threadIdx.x, ww = tx >> 6, l = tx & 63;
  const int mw = ww >> 3, nw = ww & 7, l4 = l >> 4, lm = l & 15;
  char* Ab = smem;                          // input stage, then computed tile
  char* Bb = smem + 65536;                  // panel dbuf 2x32K
  float* nfpart = (float*)(smem + 131072);  // [8][128] (dead after nA)
  float* minbuf = (float*)(smem + 131072);  // [8][64] (reuses nfpart)
  float* nAb = (float*)(smem + 135168);     // [128]

  auto issue_chunk = [&](int buf, int ch) {
#pragma unroll
    for (int u = 0; u < 2; ++u) {
      const int chunk = ww * 2 + u, ks = chunk >> 2, n = chunk & 3;
      const u16* src = Pib + ((size_t)(c << 10) + ch * 64 + n * 16 + lm) * D
                       + ks * 32 + l4 * 8;
      gload_lds16(src, Bb + buf * 32768 + chunk * 1024);
    }
  };

  // ---- prep: B frags from Brows (global, L2-hot)
  bfv8 bfr[2][8];
#pragma unroll
  for (int nf2 = 0; nf2 < 2; ++nf2)
#pragma unroll
    for (int ks = 0; ks < 8; ++ks)
      bfr[nf2][ks] = *(const bfv8*)(Brows +
          (size_t)(nw * 32 + nf2 * 16 + lm) * D + ks * 32 + l4 * 8);
  // ---- A staging: class-gathered f32 rows -> bf16 frags in LDS
  {
    const int r = tx >> 3, sg = tx & 7;
    const float* arow = Pj + ((size_t)(jt * 128 + r) * NC + c) * D + sg * 32;
#pragma unroll
    for (int g2 = 0; g2 < 4; ++g2) {
      float4 v0 = *(const float4*)(arow + g2 * 8);
      float4 v1 = *(const float4*)(arow + g2 * 8 + 4);
      uint4 w4;
      w4.x = pk2(v0.x, v0.y); w4.y = pk2(v0.z, v0.w);
      w4.z = pk2(v1.x, v1.y); w4.w = pk2(v1.z, v1.w);
      *(uint4*)(Ab + (sg * 8 + (r >> 4)) * 1024 + ((r & 15) + g2 * 16) * 16) = w4;
    }
  }
  __syncthreads();
  const bfv8* A8 = (const bfv8*)Ab;
  f32x4 acc[4][2];
#pragma unroll
  for (int mf = 0; mf < 4; ++mf) {
    acc[mf][0] = f32x4{0.f, 0.f, 0.f, 0.f};
    acc[mf][1] = f32x4{0.f, 0.f, 0.f, 0.f};
  }
#pragma unroll
  for (int ks = 0; ks < 8; ++ks)
#pragma unroll
    for (int mf = 0; mf < 4; ++mf) {
      bfv8 a = A8[(ks * 8 + mw * 4 + mf) * 64 + l];
      acc[mf][0] = __builtin_amdgcn_mfma_f32_16x16x32_bf16(a, bfr[0][ks], acc[mf][0], 0, 0, 0);
      acc[mf][1] = __builtin_amdgcn_mfma_f32_16x16x32_bf16(a, bfr[1][ks], acc[mf][1], 0, 0, 0);
    }
  float bias[2];
  if (MODE == 0) {
#pragma unroll
    for (int nf2 = 0; nf2 < 2; ++nf2)
      bias[nf2] = biasv[nw * 32 + nf2 * 16 + lm];
  } else {
#pragma unroll
    for (int nf2 = 0; nf2 < 2; ++nf2) {
      float pd = 0.f;
#pragma unroll
      for (int ks = 0; ks < 8; ++ks) {
        float4 b0 = *(const float4*)(biasv + ks * 32 + l4 * 8);
        float4 b1 = *(const float4*)(biasv + ks * 32 + l4 * 8 + 4);
        pd = fmaf(b0.x, bf2f((u16)bfr[nf2][ks][0]), pd);
        pd = fmaf(b0.y, bf2f((u16)bfr[nf2][ks][1]), pd);
        pd = fmaf(b0.z, bf2f((u16)bfr[nf2][ks][2]), pd);
        pd = fmaf(b0.w, bf2f((u16)bfr[nf2][ks][3]), pd);
        pd = fmaf(b1.x, bf2f((u16)bfr[nf2][ks][4]), pd);
        pd = fmaf(b1.y, bf2f((u16)bfr[nf2][ks][5]), pd);
        pd = fmaf(b1.z, bf2f((u16)bfr[nf2][ks][6]), pd);
        pd = fmaf(b1.w, bf2f((u16)bfr[nf2][ks][7]), pd);
      }
      pd += __shfl_xor(pd, 16, 64);
      pd += __shfl_xor(pd, 32, 64);
      bias[nf2] = -pd;
    }
  }
  __syncthreads();   // all MFMA reads of Ab done before tile overwrite
  issue_chunk(0, 0); // prefetch panel chunk 0 (overlaps tile store)
  // ---- store computed tile to LDS in A-frag order + rounded row norms
  u16* tile = (u16*)Ab;
#pragma unroll
  for (int mf = 0; mf < 4; ++mf)
#pragma unroll
    for (int rr = 0; rr < 4; ++rr) {
      const int j = mw * 64 + mf * 16 + l4 * 4 + rr;
      float v2 = 0.f;
#pragma unroll
      for (int nf2 = 0; nf2 < 2; ++nf2) {
        const float v = acc[mf][nf2][rr] + bias[nf2];
        const u16 hv = f2bf(v);
        tile[(((nw * 8 + mw * 4 + mf) << 6) + ((nf2 * 2 + (lm >> 3)) << 4)
              + l4 * 4 + rr) * 8 + (lm & 7)] = hv;
        const float vr = bf2f(hv);
        v2 = fmaf(vr, vr, v2);
      }
      v2 += __shfl_xor(v2, 1, 64);
      v2 += __shfl_xor(v2, 2, 64);
      v2 += __shfl_xor(v2, 4, 64);
      v2 += __shfl_xor(v2, 8, 64);
      if (lm == 0) nfpart[nw * 128 + j] = v2;
    }
  __syncthreads();   // tile + nfpart visible; chunk-0 loads drained
  if (tx < 128) {
    float s = 0.f;
#pragma unroll
    for (int q = 0; q < 8; ++q) s += nfpart[q * 128 + tx];
    nAb[tx] = s;
  }
  __syncthreads();
  // ---- distance loop over 16 i-chunks of 64
  const int jw = ww >> 1, iw = ww & 1;
  const float* nBc = nB + (c << 10);
  const size_t obase = (size_t)(c * 8 + jt) * 1024;
  for (int ch = 0; ch < 16; ++ch) {
    if (ch < 15) issue_chunk((ch + 1) & 1, ch + 1);
    const bfv8* B8 = (const bfv8*)(Bb + (ch & 1) * 32768);
    f32x4 a2[2];
    a2[0] = f32x4{0.f, 0.f, 0.f, 0.f};
    a2[1] = f32x4{0.f, 0.f, 0.f, 0.f};
#pragma unroll
    for (int ks = 0; ks < 8; ++ks) {
      bfv8 a = A8[(ks * 8 + jw) * 64 + l];
#pragma unroll
      for (int t = 0; t < 2; ++t) {
        bfv8 b = B8[(ks * 4 + iw * 2 + t) * 64 + l];
        a2[t] = __builtin_amdgcn_mfma_f32_16x16x32_bf16(a, b, a2[t], 0, 0, 0);
      }
    }
#pragma unroll
    for (int t = 0; t < 2; ++t) {
      const int ig = iw * 2 + t;
      const float nb = nBc[ch * 64 + ig * 16 + lm];
      float mm = 3.0e38f;
#pragma unroll
      for (int rr = 0; rr < 4; ++rr) {
        const int j = jw * 16 + l4 * 4 + rr;
        const float dd = nb + nAb[j] - 2.0f * a2[t][rr];
        mm = fminf(mm, dd);
      }
      mm = fminf(mm, __shfl_xor(mm, 16, 64));
      mm = fminf(mm, __shfl_xor(mm, 32, 64));
      if (l4 == 0) minbuf[jw * 64 + ig * 16 + lm] = mm;
    }
    __syncthreads();
    if (tx < 64) {
      float m = minbuf[tx];
#pragma unroll
      for (int q = 1; q < 8; ++q) m = fminf(m, minbuf[q * 64 + tx]);
      pmind[obase + ch * 64 + tx] = m;
    }
    __syncthreads();
  }
}

// K0: blocks 0..255 = convnorm(p2 -> p2b, n2); block 256 = W -> bf16
__global__ __launch_bounds__(1024, 1) void k0_kernel(
    const float* __restrict__ p2, u16* __restrict__ p2b,
    float* __restrict__ n2, const float* __restrict__ W,
    u16* __restrict__ Wb) {
  if (blockIdx.x < 256) {
    convnorm_role(p2, p2b, n2, blockIdx.x);
  } else {
    const int t = threadIdx.x;
#pragma unroll
    for (int k = 0; k < 64; ++k) Wb[k * 1024 + t] = f2bf(W[k * 1024 + t]);
  }
}

// K1: block 0 = gj; 1..512 = dist dir=1 (F in-block); 513..768 = convnorm p1
__global__ __launch_bounds__(1024, 1) void k1_kernel(
    const float* __restrict__ p1, const float* __restrict__ W,
    const u16* __restrict__ Wb, const float* __restrict__ bv,
    const u16* __restrict__ p2b, const float* __restrict__ n2,
    float* __restrict__ pmin1, float* __restrict__ IWa,
    u16* __restrict__ p1b, float* __restrict__ n1) {
  extern __shared__ char smem[];
  const int b = blockIdx.x;
  if (b == 0) {
    gj_body(W, IWa, smem);
  } else if (b <= 512) {
    distp_body<0>(p1, Wb, bv, p2b, n2, pmin1, b - 1, smem);
  } else {
    convnorm_role(p1, p1b, n1, b - 513);
  }
}

// Newton-Schulz: R = 2I - W*X ; Y = X*R -> bf16
__global__ __launch_bounds__(256) void nr_residual(const float* __restrict__ W,
                                                   const float* __restrict__ X,
                                                   float* __restrict__ R) {
  __shared__ float wrow[D];
  const int i = blockIdx.x, j = threadIdx.x;
  wrow[j] = W[i * D + j];
  __syncthreads();
  float acc = 0.f;
#pragma unroll 8
  for (int k = 0; k < D; ++k) acc = fmaf(wrow[k], X[k * D + j], acc);
  R[i * D + j] = (i == j ? 2.0f : 0.0f) - acc;
}

__global__ __launch_bounds__(256) void nr_mult_bf16(const float* __restrict__ X,
                                                    const float* __restrict__ R,
                                                    u16* __restrict__ Yb) {
  __shared__ float xrow[D];
  const int i = blockIdx.x, j = threadIdx.x;
  xrow[j] = X[i * D + j];
  __syncthreads();
  float acc = 0.f;
#pragma unroll 8
  for (int k = 0; k < D; ++k) acc = fmaf(xrow[k], R[k * D + j], acc);
  Yb[i * D + j] = f2bf(acc);
}

// K3: dist dir=0 (Q in-block from IWb)
__global__ __launch_bounds__(1024, 1) void k3_kernel(
    const float* __restrict__ p2, const u16* __restrict__ IWb,
    const float* __restrict__ bv, const u16* __restrict__ p1b,
    const float* __restrict__ n1, float* __restrict__ pmin0) {
  extern __shared__ char smem[];
  distp_body<1>(p2, IWb, bv, p1b, n1, pmin0, blockIdx.x, smem);
}

// final: out[dir*64+c] = mean_i min_jt pmin[dir][c][jt][i]
__global__ __launch_bounds__(256) void final_kernel(const float* __restrict__ pmin,
                                                    float* __restrict__ out) {
  __shared__ float ws4[4];
  const int dc = blockIdx.x, tx = threadIdx.x;
  const float* base = pmin + (size_t)dc * 8192;
  float s = 0.f;
#pragma unroll
  for (int t = 0; t < 4; ++t) {
    const int i = t * 256 + tx;
    float m = base[i];
#pragma unroll
    for (int j = 1; j < 8; ++j) m = fminf(m, base[j * 1024 + i]);
    s += m;
  }
#pragma unroll
  for (int off = 32; off; off >>= 1) s += __shfl_xor(s, off, 64);
  if ((tx & 63) == 0) ws4[tx >> 6] = s;
  __syncthreads();
  if (tx == 0)
    out[dc] = (ws4[0] + ws4[1] + ws4[2] + ws4[3]) * (1.0f / 1024.0f);
}

extern "C" void kernel_launch(void* const* d_in, const int* in_sizes, int n_in,
                              void* d_out, int out_size, void* d_ws, size_t ws_size,
                              hipStream_t stream) {
  const float* p1 = (const float*)d_in[0];
  const float* p2 = (const float*)d_in[1];
  const float* W  = (const float*)d_in[2];
  const float* bv = (const float*)d_in[3];
  float* out = (float*)d_out;
  char* ws = (char*)d_ws;
  float* n1  = (float*)(ws);                     // 256KB
  float* n2  = (float*)(ws + (256 << 10));       // 256KB
  u16* Wb    = (u16*)(ws + (512 << 10));         // 128KB
  u16* IWb   = (u16*)(ws + (640 << 10));         // 128KB
  float* IWa = (float*)(ws + (768 << 10));       // 256KB
  float* Rt  = (float*)(ws + (1024 << 10));      // 256KB
  float* pmin = (float*)(ws + (1280 << 10));     // 4MB: [dir][c][jt][1024]
  u16* p1b   = (u16*)(ws + (6u << 20));          // 32MB class-major bf16
  u16* p2b   = (u16*)(ws + (38u << 20));         // 32MB
  float* pmin0 = pmin;                 // dir 0 (source: p1 vs Q)
  float* pmin1 = pmin + 524288;        // dir 1 (target: p2 vs F)

  hipFuncSetAttribute((const void*)k1_kernel,
                      hipFuncAttributeMaxDynamicSharedMemorySize, DISTP_LDS);
  hipFuncSetAttribute((const void*)k3_kernel,
                      hipFuncAttributeMaxDynamicSharedMemorySize, DISTP_LDS);

  // K0: p2 convert + norms, W -> bf16
  k0_kernel<<<257, 1024, 0, stream>>>(p2, p2b, n2, W, Wb);
  // K1: gj inverse || dist dir=1 (self-contained F) || p1 convert + norms
  k1_kernel<<<769, 1024, DISTP_LDS, stream>>>(p1, W, Wb, bv, p2b, n2,
                                              pmin1, IWa, p1b, n1);
  // one Newton-Schulz refinement, bf16 output
  nr_residual<<<256, 256, 0, stream>>>(W, IWa, Rt);
  nr_mult_bf16<<<256, 256, 0, stream>>>(IWa, Rt, IWb);
  // K3: dist dir=0 (self-contained Q from IWb)
  k3_kernel<<<512, 1024, DISTP_LDS, stream>>>(p2, IWb, bv, p1b, n1, pmin0);
  final_kernel<<<128, 256, 0, stream>>>(pmin, out);
}

// Round 11
// 279.003 us; speedup vs baseline: 1.2426x; 1.0105x over previous
//
#include <hip/hip_runtime.h>

#define D 256
#define NC 64

using u16 = unsigned short;
using u32 = unsigned int;

typedef __attribute__((ext_vector_type(8))) short bfv8;   // 8 bf16 = 16 B
typedef __attribute__((ext_vector_type(4))) float f32x4;
typedef __attribute__((ext_vector_type(2))) int v2i;

__device__ __forceinline__ float bf2f(u32 u) {
  union { u32 i; float f; } v; v.i = u << 16; return v.f;
}
__device__ __forceinline__ u16 f2bf(float f) {
  union { float f; u32 i; } v; v.f = f;
  u32 x = v.i;
  return (u16)((x + 0x7FFFu + ((x >> 16) & 1u)) >> 16);  // RTNE
}
__device__ __forceinline__ u32 pk2(float a, float b) {
  return (u32)f2bf(a) | ((u32)f2bf(b) << 16);
}
__device__ __forceinline__ size_t cmrow(int g) {   // class-major row index
  return (size_t)(((g & 63) << 10) | (g >> 6));
}

__device__ __forceinline__ void gload_lds16(const void* src, void* dst) {
  __builtin_amdgcn_global_load_lds(
      (const __attribute__((address_space(1))) void*)src,
      (__attribute__((address_space(3))) void*)dst, 16, 0, 0);
}

#define K1_LDS 71168     // gj: 71168; distp v2 needs 70144
#define DISTP_LDS 70144  // tile/panel 64K (shared) + nfpart/minbuf 4K + nA 512

// ---------------------------------------------------------------------------
// Blocked Gauss-Jordan inverse (round-9/10 proven body, unchanged).
// ---------------------------------------------------------------------------
__device__ void gj_body(const float* __restrict__ W, float* __restrict__ IW,
                        char* smem) {
  float (*Ml)[20]    = (float(*)[20])smem;                 // 20480 B
  float (*Arow)[256] = (float(*)[256])(smem + 20480);      // 16384 B
  float (*G)[256]    = (float(*)[256])(smem + 36864);      // 16384 B
  u16*  Gfrag        = (u16*)(smem + 53248);               // 16640 B
  float (*Pinv)[20]  = (float(*)[20])(smem + 69888);       // 1280 B
  const int t = threadIdx.x, w = t >> 6, l = t & 63;
  const int lj = l & 15, lh = l >> 4;
  const int r0 = 16 * w;
  const bool lo32 = (l < 32);

  f32x4 x[16];
#pragma unroll
  for (int ct = 0; ct < 16; ++ct)
#pragma unroll
    for (int reg = 0; reg < 4; ++reg)
      x[ct][reg] = W[(size_t)(r0 + 4 * lh + reg) * D + 16 * ct + lj];

  for (int s = 0; s < 16; ++s) {
#pragma unroll
    for (int ct = 0; ct < 16; ++ct)
      if (ct == s)
#pragma unroll
        for (int reg = 0; reg < 4; ++reg)
          Ml[r0 + 4 * lh + reg][lj] = x[ct][reg];
    if (w == s) {
#pragma unroll
      for (int ct = 0; ct < 16; ++ct)
#pragma unroll
        for (int reg = 0; reg < 4; ++reg)
          Arow[4 * lh + reg][16 * ct + lj] = x[ct][reg];
    }
    bfv8 afr;
    {
      const int row = r0 + lj;
      float4 f0 = *(const float4*)&Ml[row][8 * (lh & 1)];
      float4 f1 = *(const float4*)&Ml[row][8 * (lh & 1) + 4];
      const float fv[8] = {f0.x, f0.y, f0.z, f0.w, f1.x, f1.y, f1.z, f1.w};
      union { bfv8 v; u16 e[8]; } A;
      if (lh < 2) {
#pragma unroll
        for (int e = 0; e < 8; ++e) A.e[e] = f2bf(-fv[e]);
      } else {
#pragma unroll
        for (int e = 0; e < 8; ++e) {
          const float hi = bf2f(f2bf(fv[e]));
          A.e[e] = f2bf(-(fv[e] - hi));
        }
      }
      afr = A.v;
    }
    __syncthreads();
    if (t < 16) {
      float p[16];
      {
        float4 rr0 = *(const float4*)&Ml[16 * s + t][0];
        float4 rr1 = *(const float4*)&Ml[16 * s + t][4];
        float4 rr2 = *(const float4*)&Ml[16 * s + t][8];
        float4 rr3 = *(const float4*)&Ml[16 * s + t][12];
        p[0] = rr0.x; p[1] = rr0.y; p[2] = rr0.z; p[3] = rr0.w;
        p[4] = rr1.x; p[5] = rr1.y; p[6] = rr1.z; p[7] = rr1.w;
        p[8] = rr2.x; p[9] = rr2.y; p[10] = rr2.z; p[11] = rr2.w;
        p[12] = rr3.x; p[13] = rr3.y; p[14] = rr3.z; p[15] = rr3.w;
      }
#pragma unroll
      for (int pp = 0; pp < 16; ++pp) {
        float u[16];
#pragma unroll
        for (int j = 0; j < 16; ++j)
          u[j] = __int_as_float(__builtin_amdgcn_readlane(__float_as_int(p[j]), pp));
        const float pv = u[pp];
        const float d = 1.0f / pv;
        if (t == pp) {
#pragma unroll
          for (int j = 0; j < 16; ++j) p[j] = u[j] * d;
          p[pp] = d;
        } else {
          const float md = p[pp] * d;
          u[pp] = pv + 1.0f;
#pragma unroll
          for (int j = 0; j < 16; ++j) p[j] = fmaf(-md, u[j], p[j]);
        }
      }
#pragma unroll
      for (int j = 0; j < 16; ++j) Pinv[t][j] = p[j];
    }
    __syncthreads();
    {
      const bool inC = ((l >> 2) == s);
      const int co = (l & 3) << 2;
      const int gct = l >> 2;
      const int kk = w;
      float4 g = make_float4(0.f, 0.f, 0.f, 0.f);
#pragma unroll
      for (int q = 0; q < 16; ++q) {
        const float pv = Pinv[kk][q];
        const float4 av = *(const float4*)&Arow[q][4 * l];
        g.x = fmaf(pv, av.x, g.x); g.y = fmaf(pv, av.y, g.y);
        g.z = fmaf(pv, av.z, g.z); g.w = fmaf(pv, av.w, g.w);
      }
      if (inC) {
        g.x = Pinv[kk][co + 0] + (kk == co + 0 ? 1.f : 0.f);
        g.y = Pinv[kk][co + 1] + (kk == co + 1 ? 1.f : 0.f);
        g.z = Pinv[kk][co + 2] + (kk == co + 2 ? 1.f : 0.f);
        g.w = Pinv[kk][co + 3] + (kk == co + 3 ? 1.f : 0.f);
      }
      *(float4*)&G[kk][4 * l] = g;
      const int e0 = kk & 7;
      const int lbase = 16 * (kk >> 3);
      const float gv[4] = {g.x, g.y, g.z, g.w};
#pragma unroll
      for (int cc = 0; cc < 4; ++cc) {
        const int cl = 4 * (l & 3) + cc;
        const u16 hi = f2bf(gv[cc]);
        const u16 lo = f2bf(gv[cc] - bf2f(hi));
        Gfrag[gct * 520 + (lbase + cl) * 8 + e0] = hi;
        Gfrag[gct * 520 + (32 + lbase + cl) * 8 + e0] = lo;
      }
    }
    __syncthreads();
    if (w != s) {
#pragma unroll
      for (int ct = 0; ct < 16; ++ct) {
        union { bfv8 v; uint4 u; } B1, B2;
        B1.v = *(const bfv8*)&Gfrag[ct * 520 + l * 8];
#if __has_builtin(__builtin_amdgcn_permlane32_swap)
        {
          v2i r;
          r = __builtin_amdgcn_permlane32_swap((int)B1.u.x, (int)B1.u.x, false, false);
          B2.u.x = lo32 ? (u32)r.y : (u32)r.x;
          r = __builtin_amdgcn_permlane32_swap((int)B1.u.y, (int)B1.u.y, false, false);
          B2.u.y = lo32 ? (u32)r.y : (u32)r.x;
          r = __builtin_amdgcn_permlane32_swap((int)B1.u.z, (int)B1.u.z, false, false);
          B2.u.z = lo32 ? (u32)r.y : (u32)r.x;
          r = __builtin_amdgcn_permlane32_swap((int)B1.u.w, (int)B1.u.w, false, false);
          B2.u.w = lo32 ? (u32)r.y : (u32)r.x;
        }
#else
        B2.v = *(const bfv8*)&Gfrag[ct * 520 + (l ^ 32) * 8];
#endif
        x[ct] = __builtin_amdgcn_mfma_f32_16x16x32_bf16(afr, B1.v, x[ct], 0, 0, 0);
        x[ct] = __builtin_amdgcn_mfma_f32_16x16x32_bf16(afr, B2.v, x[ct], 0, 0, 0);
      }
    } else {
#pragma unroll
      for (int ct = 0; ct < 16; ++ct) {
        if (ct == s) {
#pragma unroll
          for (int reg = 0; reg < 4; ++reg)
            x[ct][reg] = Pinv[4 * lh + reg][lj];
        } else {
#pragma unroll
          for (int reg = 0; reg < 4; ++reg)
            x[ct][reg] = G[4 * lh + reg][16 * ct + lj];
        }
      }
    }
    __syncthreads();
  }
#pragma unroll
  for (int ct = 0; ct < 16; ++ct)
#pragma unroll
    for (int reg = 0; reg < 4; ++reg)
      IW[(size_t)(r0 + 4 * lh + reg) * D + 16 * ct + lj] = x[ct][reg];
}

// ---------------------------------------------------------------------------
// convnorm: f32 row-major -> bf16 class-major + exact f32 row norms.
// ---------------------------------------------------------------------------
__device__ void convnorm_role(const float* __restrict__ P, u16* __restrict__ Pb,
                              float* __restrict__ nrm, int blk) {
  const int tx = threadIdx.x;
  const int r = tx >> 2, q = tx & 3;
  const int g = blk * 256 + r;
  const float* src = P + (size_t)g * D + q * 64;
  u16* dst = Pb + cmrow(g) * D + q * 64;
  float ss = 0.f;
#pragma unroll
  for (int g4 = 0; g4 < 8; ++g4) {
    float4 v0 = *(const float4*)(src + g4 * 8);
    float4 v1 = *(const float4*)(src + g4 * 8 + 4);
    ss = fmaf(v0.x, v0.x, fmaf(v0.y, v0.y, fmaf(v0.z, v0.z, fmaf(v0.w, v0.w, ss))));
    ss = fmaf(v1.x, v1.x, fmaf(v1.y, v1.y, fmaf(v1.z, v1.z, fmaf(v1.w, v1.w, ss))));
    uint4 w4;
    w4.x = pk2(v0.x, v0.y); w4.y = pk2(v0.z, v0.w);
    w4.z = pk2(v1.x, v1.y); w4.w = pk2(v1.z, v1.w);
    *(uint4*)(dst + g4 * 8) = w4;
  }
  ss += __shfl_xor(ss, 1, 64);
  ss += __shfl_xor(ss, 2, 64);
  if (q == 0) nrm[cmrow(g)] = ss;
}

// ---------------------------------------------------------------------------
// distp v2: fused {tile prep + distance + min} per (class, j-tile), 1024 thr.
// Change vs r10: A-slice in REGISTERS (afr[2][8], loaded once from the tile),
// each B read feeds 2 MFMAs (0.5 LDS reads/MFMA); panel dbuf REUSES the
// tile's 64KB LDS. Wave = (jw 0..3: 32 j's) x (iw 0..3: 16-i group).
// ---------------------------------------------------------------------------
template <int MODE>
__device__ void distp_body(const float* __restrict__ Pj,
                           const u16* __restrict__ Brows,
                           const float* __restrict__ biasv,
                           const u16* __restrict__ Pib,
                           const float* __restrict__ nB,
                           float* __restrict__ pmind, int bid, char* smem) {
  const int lb = (bid & 7) * 64 + (bid >> 3);   // XCD swizzle: class->XCD
  const int c = lb >> 3, jt = lb & 7;
  const int tx = threadIdx.x, ww = tx >> 6, l = tx & 63;
  const int mw = ww >> 3, nw = ww & 7, l4 = l >> 4, lm = l & 15;
  char* Ab = smem;                          // A-stage -> tile -> panel dbuf
  float* nfpart = (float*)(smem + 65536);   // [8][128] (tile-store phase)
  float* minbuf = (float*)(smem + 65536);   // [4][64]  (dist loop, disjoint)
  float* nAb = (float*)(smem + 69632);      // [128]

  auto issue_chunk = [&](int buf, int ch) {
#pragma unroll
    for (int u = 0; u < 2; ++u) {
      const int chunk = ww * 2 + u, ks = chunk >> 2, n = chunk & 3;
      const u16* src = Pib + ((size_t)(c << 10) + ch * 64 + n * 16 + lm) * D
                       + ks * 32 + l4 * 8;
      gload_lds16(src, Ab + buf * 32768 + chunk * 1024);
    }
  };

  // ---- prep: B frags from Brows (global, L2-hot) — r10 verbatim
  bfv8 bfr[2][8];
#pragma unroll
  for (int nf2 = 0; nf2 < 2; ++nf2)
#pragma unroll
    for (int ks = 0; ks < 8; ++ks)
      bfr[nf2][ks] = *(const bfv8*)(Brows +
          (size_t)(nw * 32 + nf2 * 16 + lm) * D + ks * 32 + l4 * 8);
  // ---- A staging: class-gathered f32 rows -> bf16 frags in LDS
  {
    const int r = tx >> 3, sg = tx & 7;
    const float* arow = Pj + ((size_t)(jt * 128 + r) * NC + c) * D + sg * 32;
#pragma unroll
    for (int g2 = 0; g2 < 4; ++g2) {
      float4 v0 = *(const float4*)(arow + g2 * 8);
      float4 v1 = *(const float4*)(arow + g2 * 8 + 4);
      uint4 w4;
      w4.x = pk2(v0.x, v0.y); w4.y = pk2(v0.z, v0.w);
      w4.z = pk2(v1.x, v1.y); w4.w = pk2(v1.z, v1.w);
      *(uint4*)(Ab + (sg * 8 + (r >> 4)) * 1024 + ((r & 15) + g2 * 16) * 16) = w4;
    }
  }
  __syncthreads();
  const bfv8* A8 = (const bfv8*)Ab;
  f32x4 acc[4][2];
#pragma unroll
  for (int mf = 0; mf < 4; ++mf) {
    acc[mf][0] = f32x4{0.f, 0.f, 0.f, 0.f};
    acc[mf][1] = f32x4{0.f, 0.f, 0.f, 0.f};
  }
#pragma unroll
  for (int ks = 0; ks < 8; ++ks)
#pragma unroll
    for (int mf = 0; mf < 4; ++mf) {
      bfv8 a = A8[(ks * 8 + mw * 4 + mf) * 64 + l];
      acc[mf][0] = __builtin_amdgcn_mfma_f32_16x16x32_bf16(a, bfr[0][ks], acc[mf][0], 0, 0, 0);
      acc[mf][1] = __builtin_amdgcn_mfma_f32_16x16x32_bf16(a, bfr[1][ks], acc[mf][1], 0, 0, 0);
    }
  float bias[2];
  if (MODE == 0) {
#pragma unroll
    for (int nf2 = 0; nf2 < 2; ++nf2)
      bias[nf2] = biasv[nw * 32 + nf2 * 16 + lm];
  } else {
#pragma unroll
    for (int nf2 = 0; nf2 < 2; ++nf2) {
      float pd = 0.f;
#pragma unroll
      for (int ks = 0; ks < 8; ++ks) {
        float4 b0 = *(const float4*)(biasv + ks * 32 + l4 * 8);
        float4 b1 = *(const float4*)(biasv + ks * 32 + l4 * 8 + 4);
        pd = fmaf(b0.x, bf2f((u16)bfr[nf2][ks][0]), pd);
        pd = fmaf(b0.y, bf2f((u16)bfr[nf2][ks][1]), pd);
        pd = fmaf(b0.z, bf2f((u16)bfr[nf2][ks][2]), pd);
        pd = fmaf(b0.w, bf2f((u16)bfr[nf2][ks][3]), pd);
        pd = fmaf(b1.x, bf2f((u16)bfr[nf2][ks][4]), pd);
        pd = fmaf(b1.y, bf2f((u16)bfr[nf2][ks][5]), pd);
        pd = fmaf(b1.z, bf2f((u16)bfr[nf2][ks][6]), pd);
        pd = fmaf(b1.w, bf2f((u16)bfr[nf2][ks][7]), pd);
      }
      pd += __shfl_xor(pd, 16, 64);
      pd += __shfl_xor(pd, 32, 64);
      bias[nf2] = -pd;
    }
  }
  __syncthreads();   // all MFMA reads of Ab done before tile overwrite
  // ---- store computed tile to LDS (A-frag order, r10 verbatim) + norms
  u16* tile = (u16*)Ab;
#pragma unroll
  for (int mf = 0; mf < 4; ++mf)
#pragma unroll
    for (int rr = 0; rr < 4; ++rr) {
      const int j = mw * 64 + mf * 16 + l4 * 4 + rr;
      float v2 = 0.f;
#pragma unroll
      for (int nf2 = 0; nf2 < 2; ++nf2) {
        const float v = acc[mf][nf2][rr] + bias[nf2];
        const u16 hv = f2bf(v);
        tile[(((nw * 8 + mw * 4 + mf) << 6) + ((nf2 * 2 + (lm >> 3)) << 4)
              + l4 * 4 + rr) * 8 + (lm & 7)] = hv;
        const float vr = bf2f(hv);
        v2 = fmaf(vr, vr, v2);
      }
      v2 += __shfl_xor(v2, 1, 64);
      v2 += __shfl_xor(v2, 2, 64);
      v2 += __shfl_xor(v2, 4, 64);
      v2 += __shfl_xor(v2, 8, 64);
      if (lm == 0) nfpart[nw * 128 + j] = v2;
    }
  __syncthreads();   // tile visible to all
  // ---- load this wave's A-slice to registers (tile dead after this)
  const int jw = ww >> 2, iw = ww & 3;
  bfv8 afr[2][8];
#pragma unroll
  for (int jj = 0; jj < 2; ++jj)
#pragma unroll
    for (int ks = 0; ks < 8; ++ks)
      afr[jj][ks] = A8[(ks * 8 + jw * 2 + jj) * 64 + l];
  __syncthreads();   // all afr loads done before panel overwrites tile
  issue_chunk(0, 0); // chunk 0 into buf0 (tile region, now dead)
  if (tx < 128) {
    float s = 0.f;
#pragma unroll
    for (int q = 0; q < 8; ++q) s += nfpart[q * 128 + tx];
    nAb[tx] = s;
  }
  __syncthreads();   // chunk-0 loads drained (barrier vmcnt drain); nAb ready
  float naj[2][4];
#pragma unroll
  for (int jj = 0; jj < 2; ++jj)
#pragma unroll
    for (int rr = 0; rr < 4; ++rr)
      naj[jj][rr] = nAb[jw * 32 + jj * 16 + l4 * 4 + rr];
  // ---- distance loop over 16 i-chunks of 64
  const float* nBc = nB + (c << 10);
  const size_t obase = (size_t)(c * 8 + jt) * 1024;
  for (int ch = 0; ch < 16; ++ch) {
    if (ch < 15) issue_chunk((ch + 1) & 1, ch + 1);
    const bfv8* B8 = (const bfv8*)(Ab + (ch & 1) * 32768);
    f32x4 a2[2];
    a2[0] = f32x4{0.f, 0.f, 0.f, 0.f};
    a2[1] = f32x4{0.f, 0.f, 0.f, 0.f};
#pragma unroll
    for (int ks = 0; ks < 8; ++ks) {
      bfv8 b = B8[(ks * 4 + iw) * 64 + l];
      a2[0] = __builtin_amdgcn_mfma_f32_16x16x32_bf16(afr[0][ks], b, a2[0], 0, 0, 0);
      a2[1] = __builtin_amdgcn_mfma_f32_16x16x32_bf16(afr[1][ks], b, a2[1], 0, 0, 0);
    }
    const float nb = nBc[ch * 64 + iw * 16 + lm];
    float mm = 3.0e38f;
#pragma unroll
    for (int jj = 0; jj < 2; ++jj)
#pragma unroll
      for (int rr = 0; rr < 4; ++rr) {
        const float dd = nb + naj[jj][rr] - 2.0f * a2[jj][rr];
        mm = fminf(mm, dd);
      }
    mm = fminf(mm, __shfl_xor(mm, 16, 64));
    mm = fminf(mm, __shfl_xor(mm, 32, 64));
    if (l4 == 0) minbuf[jw * 64 + iw * 16 + lm] = mm;
    __syncthreads();
    if (tx < 64) {
      float m = minbuf[tx];
#pragma unroll
      for (int q = 1; q < 4; ++q) m = fminf(m, minbuf[q * 64 + tx]);
      pmind[obase + ch * 64 + tx] = m;
    }
    __syncthreads();
  }
}

// K0: blocks 0..255 = convnorm(p2 -> p2b, n2); block 256 = W -> bf16
__global__ __launch_bounds__(1024, 1) void k0_kernel(
    const float* __restrict__ p2, u16* __restrict__ p2b,
    float* __restrict__ n2, const float* __restrict__ W,
    u16* __restrict__ Wb) {
  if (blockIdx.x < 256) {
    convnorm_role(p2, p2b, n2, blockIdx.x);
  } else {
    const int t = threadIdx.x;
#pragma unroll
    for (int k = 0; k < 64; ++k) Wb[k * 1024 + t] = f2bf(W[k * 1024 + t]);
  }
}

// K1: block 0 = gj; 1..512 = dist dir=1 (F in-block); 513..768 = convnorm p1
__global__ __launch_bounds__(1024, 1) void k1_kernel(
    const float* __restrict__ p1, const float* __restrict__ W,
    const u16* __restrict__ Wb, const float* __restrict__ bv,
    const u16* __restrict__ p2b, const float* __restrict__ n2,
    float* __restrict__ pmin1, float* __restrict__ IWa,
    u16* __restrict__ p1b, float* __restrict__ n1) {
  extern __shared__ char smem[];
  const int b = blockIdx.x;
  if (b == 0) {
    gj_body(W, IWa, smem);
  } else if (b <= 512) {
    distp_body<0>(p1, Wb, bv, p2b, n2, pmin1, b - 1, smem);
  } else {
    convnorm_role(p1, p1b, n1, b - 513);
  }
}

// Newton-Schulz: R = 2I - W*X ; Y = X*R -> bf16
__global__ __launch_bounds__(256) void nr_residual(const float* __restrict__ W,
                                                   const float* __restrict__ X,
                                                   float* __restrict__ R) {
  __shared__ float wrow[D];
  const int i = blockIdx.x, j = threadIdx.x;
  wrow[j] = W[i * D + j];
  __syncthreads();
  float acc = 0.f;
#pragma unroll 8
  for (int k = 0; k < D; ++k) acc = fmaf(wrow[k], X[k * D + j], acc);
  R[i * D + j] = (i == j ? 2.0f : 0.0f) - acc;
}

__global__ __launch_bounds__(256) void nr_mult_bf16(const float* __restrict__ X,
                                                    const float* __restrict__ R,
                                                    u16* __restrict__ Yb) {
  __shared__ float xrow[D];
  const int i = blockIdx.x, j = threadIdx.x;
  xrow[j] = X[i * D + j];
  __syncthreads();
  float acc = 0.f;
#pragma unroll 8
  for (int k = 0; k < D; ++k) acc = fmaf(xrow[k], R[k * D + j], acc);
  Yb[i * D + j] = f2bf(acc);
}

// K3: dist dir=0 (Q in-block from IWb)
__global__ __launch_bounds__(1024, 1) void k3_kernel(
    const float* __restrict__ p2, const u16* __restrict__ IWb,
    const float* __restrict__ bv, const u16* __restrict__ p1b,
    const float* __restrict__ n1, float* __restrict__ pmin0) {
  extern __shared__ char smem[];
  distp_body<1>(p2, IWb, bv, p1b, n1, pmin0, blockIdx.x, smem);
}

// final: out[dir*64+c] = mean_i min_jt pmin[dir][c][jt][i]
__global__ __launch_bounds__(256) void final_kernel(const float* __restrict__ pmin,
                                                    float* __restrict__ out) {
  __shared__ float ws4[4];
  const int dc = blockIdx.x, tx = threadIdx.x;
  const float* base = pmin + (size_t)dc * 8192;
  float s = 0.f;
#pragma unroll
  for (int t = 0; t < 4; ++t) {
    const int i = t * 256 + tx;
    float m = base[i];
#pragma unroll
    for (int j = 1; j < 8; ++j) m = fminf(m, base[j * 1024 + i]);
    s += m;
  }
#pragma unroll
  for (int off = 32; off; off >>= 1) s += __shfl_xor(s, off, 64);
  if ((tx & 63) == 0) ws4[tx >> 6] = s;
  __syncthreads();
  if (tx == 0)
    out[dc] = (ws4[0] + ws4[1] + ws4[2] + ws4[3]) * (1.0f / 1024.0f);
}

extern "C" void kernel_launch(void* const* d_in, const int* in_sizes, int n_in,
                              void* d_out, int out_size, void* d_ws, size_t ws_size,
                              hipStream_t stream) {
  const float* p1 = (const float*)d_in[0];
  const float* p2 = (const float*)d_in[1];
  const float* W  = (const float*)d_in[2];
  const float* bv = (const float*)d_in[3];
  float* out = (float*)d_out;
  char* ws = (char*)d_ws;
  float* n1  = (float*)(ws);                     // 256KB
  float* n2  = (float*)(ws + (256 << 10));       // 256KB
  u16* Wb    = (u16*)(ws + (512 << 10));         // 128KB
  u16* IWb   = (u16*)(ws + (640 << 10));         // 128KB
  float* IWa = (float*)(ws + (768 << 10));       // 256KB
  float* Rt  = (float*)(ws + (1024 << 10));      // 256KB
  float* pmin = (float*)(ws + (1280 << 10));     // 4MB: [dir][c][jt][1024]
  u16* p1b   = (u16*)(ws + (6u << 20));          // 32MB class-major bf16
  u16* p2b   = (u16*)(ws + (38u << 20));         // 32MB
  float* pmin0 = pmin;                 // dir 0 (source: p1 vs Q)
  float* pmin1 = pmin + 524288;        // dir 1 (target: p2 vs F)

  hipFuncSetAttribute((const void*)k1_kernel,
                      hipFuncAttributeMaxDynamicSharedMemorySize, K1_LDS);
  hipFuncSetAttribute((const void*)k3_kernel,
                      hipFuncAttributeMaxDynamicSharedMemorySize, DISTP_LDS);

  // K0: p2 convert + norms, W -> bf16
  k0_kernel<<<257, 1024, 0, stream>>>(p2, p2b, n2, W, Wb);
  // K1: gj inverse || dist dir=1 (self-contained F) || p1 convert + norms
  k1_kernel<<<769, 1024, K1_LDS, stream>>>(p1, W, Wb, bv, p2b, n2,
                                           pmin1, IWa, p1b, n1);
  // one Newton-Schulz refinement, bf16 output
  nr_residual<<<256, 256, 0, stream>>>(W, IWa, Rt);
  nr_mult_bf16<<<256, 256, 0, stream>>>(IWa, Rt, IWb);
  // K3: dist dir=0 (self-contained Q from IWb)
  k3_kernel<<<512, 1024, DISTP_LDS, stream>>>(p2, IWb, bv, p1b, n1, pmin0);
  final_kernel<<<128, 256, 0, stream>>>(pmin, out);
}